// Round 4
// baseline (660.784 us; speedup 1.0000x reference)
//
#include <hip/hip_runtime.h>
#include <math.h>

typedef __attribute__((ext_vector_type(8))) short bshort8;
typedef __attribute__((ext_vector_type(4))) float f32x4;

#define DI __device__ __forceinline__

DI unsigned short f2bf(float x) {
    unsigned int u = __builtin_bit_cast(unsigned int, x);
    u += 0x7fffu + ((u >> 16) & 1u);
    return (unsigned short)(u >> 16);
}

DI bshort8 pack8(const float* v) {
    bshort8 r;
    #pragma unroll
    for (int j = 0; j < 8; j++) r[j] = (short)f2bf(v[j]);
    return r;
}

DI f32x4 mfma16(bshort8 a, bshort8 b, f32x4 c) {
    return __builtin_amdgcn_mfma_f32_16x16x32_bf16(a, b, c, 0, 0, 0);
}

// ---- composite (bilinear resize N->112, align_corners=False) + 8x8 avgpool stencils ----
__device__ const float W14[14][3] = {
    {0.875f, 0.125f, 0.f},
    {0.125f, 0.75f, 0.125f}, {0.125f, 0.75f, 0.125f}, {0.125f, 0.75f, 0.125f},
    {0.125f, 0.75f, 0.125f}, {0.125f, 0.75f, 0.125f}, {0.125f, 0.75f, 0.125f},
    {0.125f, 0.75f, 0.125f}, {0.125f, 0.75f, 0.125f}, {0.125f, 0.75f, 0.125f},
    {0.125f, 0.75f, 0.125f}, {0.125f, 0.75f, 0.125f}, {0.125f, 0.75f, 0.125f},
    {0.125f, 0.875f, 0.f}};
__device__ const float W28[14][4] = {
    {0.5f, 0.4375f, 0.0625f, 0.f},
    {0.0625f, 0.4375f, 0.4375f, 0.0625f}, {0.0625f, 0.4375f, 0.4375f, 0.0625f},
    {0.0625f, 0.4375f, 0.4375f, 0.0625f}, {0.0625f, 0.4375f, 0.4375f, 0.0625f},
    {0.0625f, 0.4375f, 0.4375f, 0.0625f}, {0.0625f, 0.4375f, 0.4375f, 0.0625f},
    {0.0625f, 0.4375f, 0.4375f, 0.0625f}, {0.0625f, 0.4375f, 0.4375f, 0.0625f},
    {0.0625f, 0.4375f, 0.4375f, 0.0625f}, {0.0625f, 0.4375f, 0.4375f, 0.0625f},
    {0.0625f, 0.4375f, 0.4375f, 0.0625f}, {0.0625f, 0.4375f, 0.4375f, 0.0625f},
    {0.0625f, 0.4375f, 0.5f, 0.f}};
__device__ const float W56[14][6] = {
    {0.25f, 0.25f, 0.25f, 0.21875f, 0.03125f, 0.f},
    {0.03125f, 0.21875f, 0.25f, 0.25f, 0.21875f, 0.03125f},
    {0.03125f, 0.21875f, 0.25f, 0.25f, 0.21875f, 0.03125f},
    {0.03125f, 0.21875f, 0.25f, 0.25f, 0.21875f, 0.03125f},
    {0.03125f, 0.21875f, 0.25f, 0.25f, 0.21875f, 0.03125f},
    {0.03125f, 0.21875f, 0.25f, 0.25f, 0.21875f, 0.03125f},
    {0.03125f, 0.21875f, 0.25f, 0.25f, 0.21875f, 0.03125f},
    {0.03125f, 0.21875f, 0.25f, 0.25f, 0.21875f, 0.03125f},
    {0.03125f, 0.21875f, 0.25f, 0.25f, 0.21875f, 0.03125f},
    {0.03125f, 0.21875f, 0.25f, 0.25f, 0.21875f, 0.03125f},
    {0.03125f, 0.21875f, 0.25f, 0.25f, 0.21875f, 0.03125f},
    {0.03125f, 0.21875f, 0.25f, 0.25f, 0.21875f, 0.03125f},
    {0.03125f, 0.21875f, 0.25f, 0.25f, 0.21875f, 0.03125f},
    {0.03125f, 0.21875f, 0.25f, 0.25f, 0.25f, 0.f}};

// -------- pooled-feature bodies; pf layout [cin][1568], col = b*196 + r --------
template <int N, int C, int TAPS>
DI void pool_body(const float* __restrict__ src, float* __restrict__ dst,
                  unsigned blk, unsigned t)
{
    unsigned id = blk * 256u + t;
    unsigned p = id / 196u;
    unsigned r = id - p * 196u;
    unsigned ti = r / 14u, tj = r - ti * 14u;
    unsigned b = p / C, cin = p - b * C;
    const float* plane = src + (size_t)p * (N * N);
    float acc = 0.f;
    if constexpr (N == 112) {
        const float4* p4 = (const float4*)(plane + (size_t)(ti * 8) * 112 + tj * 8);
        #pragma unroll
        for (int i = 0; i < 8; i++) {
            float4 u = p4[i * 28];
            float4 v = p4[i * 28 + 1];
            acc += (u.x + u.y) + (u.z + u.w) + (v.x + v.y) + (v.z + v.w);
        }
        acc *= (1.f / 64.f);
    } else {
        constexpr int STRIDE = N / 14;
        const float (*WT)[TAPS] = (N == 14) ? (const float (*)[TAPS])W14
                                : (N == 28) ? (const float (*)[TAPS])W28
                                            : (const float (*)[TAPS])W56;
        int hs = (int)(STRIDE * ti) - 1; if (hs < 0) hs = 0;
        int ws = (int)(STRIDE * tj) - 1; if (ws < 0) ws = 0;
        float wh[TAPS], ww[TAPS];
        #pragma unroll
        for (int i = 0; i < TAPS; i++) { wh[i] = WT[ti][i]; ww[i] = WT[tj][i]; }
        #pragma unroll
        for (int i = 0; i < TAPS; i++) {
            int hi = hs + i; if (hi > N - 1) hi = N - 1;
            const float* row = plane + (size_t)hi * N;
            float rs = 0.f;
            #pragma unroll
            for (int j = 0; j < TAPS; j++) {
                int wj = ws + j; if (wj > N - 1) wj = N - 1;
                rs += ww[j] * row[wj];
            }
            acc += wh[i] * rs;
        }
    }
    dst[(size_t)cin * 1568 + b * 196 + r] = acc;
}

DI void c5_mean_body(const float* __restrict__ c5, float* __restrict__ pooled,
                     unsigned blk, unsigned t)
{
    int wid = t >> 6, lane = t & 63;
    int p = blk * 4 + wid;
    const float* plane = c5 + (size_t)p * 196;
    float v = plane[lane] + plane[64 + lane] + plane[128 + lane];
    if (lane < 4) v += plane[192 + lane];
    #pragma unroll
    for (int off = 32; off > 0; off >>= 1) v += __shfl_xor(v, off, 64);
    if (lane == 0) pooled[p] = v * (1.f / 196.f);
}

// -------- K1: all four scale pools + c5 mean in ONE dispatch --------
__global__ __launch_bounds__(256) void pool_all(
    const float* __restrict__ c2, const float* __restrict__ c3,
    const float* __restrict__ c4, const float* __restrict__ c5,
    float* __restrict__ pf0, float* __restrict__ pf1,
    float* __restrict__ pf2, float* __restrict__ pf3,
    float* __restrict__ pooled)
{
    unsigned bx = blockIdx.x, t = threadIdx.x;
    if (bx < 1568u)       pool_body<112, 256, 8>(c2, pf0, bx, t);
    else if (bx < 4704u)  pool_body<56, 512, 6>(c3, pf1, bx - 1568u, t);
    else if (bx < 10976u) pool_body<28, 1024, 4>(c4, pf2, bx - 4704u, t);
    else if (bx < 23520u) pool_body<14, 2048, 3>(c5, pf3, bx - 10976u, t);
    else                  c5_mean_body(c5, pooled, bx - 23520u, t);
}

// -------- K2a: partial GEMV for sw MLP layer 1 (split-K) + hoisted Wa (y>=8) --------
__global__ __launch_bounds__(512) void sw_part(
    const float* __restrict__ pooled, const float* __restrict__ sp_w1,
    float* __restrict__ partial,
    const float* __restrict__ gat_W, const float* __restrict__ gat_a,
    float* __restrict__ Wa)
{
    int t = threadIdx.x;
    if (blockIdx.y >= 8) {
        // Wa[h][which][c] = dot(gat_W[h][c][:], a_which); 16 blocks, one (h,q) each
        int e = (blockIdx.y - 8) * 8 + blockIdx.x;   // [0,16)
        int h = e >> 2, q = e & 3;
        __shared__ float a1[256], a2[256];
        if (t < 256) { a1[t] = gat_a[h * 512 + t]; a2[t] = gat_a[h * 512 + 256 + t]; }
        __syncthreads();
        int w = t >> 6, lane = t & 63;
        #pragma unroll
        for (int ci = 0; ci < 8; ci++) {
            int c = q * 64 + w * 8 + ci;
            const float* row = gat_W + (size_t)h * 65536 + (size_t)c * 256;
            float p1 = 0.f, p2 = 0.f;
            #pragma unroll
            for (int jj = 0; jj < 4; jj++) {
                float v = row[lane + 64 * jj];
                p1 += v * a1[lane + 64 * jj];
                p2 += v * a2[lane + 64 * jj];
            }
            #pragma unroll
            for (int off = 32; off > 0; off >>= 1) {
                p1 += __shfl_xor(p1, off, 64);
                p2 += __shfl_xor(p2, off, 64);
            }
            if (lane == 0) { Wa[h * 512 + c] = p1; Wa[h * 512 + 256 + c] = p2; }
        }
        return;
    }
    int b = blockIdx.x, kc = blockIdx.y;
    __shared__ float ps[256];
    if (t < 256) ps[t] = pooled[b * 2048 + kc * 256 + t];
    __syncthreads();
    float acc = 0.f;
    const float* w = sp_w1 + (size_t)(kc * 256) * 512 + t;
    #pragma unroll 8
    for (int c = 0; c < 256; c++) acc += ps[c] * w[(size_t)c * 512];
    partial[((size_t)b * 8 + kc) * 512 + t] = acc;
}

// -------- K2b: finish sw MLP, write sw + beff; also hoisted ldot = lemb @ Wa^T --------
__global__ __launch_bounds__(512) void sw_fin(
    const float* __restrict__ partial, const float* __restrict__ sp_b1,
    const float* __restrict__ sp_w2, const float* __restrict__ sp_b2,
    const float* __restrict__ lb0, const float* __restrict__ lb1,
    const float* __restrict__ lb2, const float* __restrict__ lb3,
    const float* __restrict__ lemb, const float* __restrict__ Wa,
    float* __restrict__ sw_out, float* __restrict__ beff,
    float* __restrict__ ldot)
{
    int b = blockIdx.x, t = threadIdx.x;
    __shared__ float h[512];
    __shared__ float s4s[4];
    __shared__ float swl[4];
    float a = sp_b1[t];
    #pragma unroll
    for (int kc = 0; kc < 8; kc++) a += partial[((size_t)b * 8 + kc) * 512 + t];
    h[t] = fmaxf(a, 0.f);
    __syncthreads();
    int wv = t >> 6, lane = t & 63;
    if (wv < 4) {
        float acc = 0.f;
        #pragma unroll
        for (int i = 0; i < 8; i++) {
            int idx = lane + 64 * i;
            acc += h[idx] * sp_w2[idx * 4 + wv];
        }
        #pragma unroll
        for (int off = 32; off > 0; off >>= 1) acc += __shfl_xor(acc, off, 64);
        if (lane == 0) s4s[wv] = acc + sp_b2[wv];
    }
    __syncthreads();
    if (t == 0) {
        float mx = fmaxf(fmaxf(s4s[0], s4s[1]), fmaxf(s4s[2], s4s[3]));
        float e0 = expf(s4s[0] - mx), e1 = expf(s4s[1] - mx);
        float e2 = expf(s4s[2] - mx), e3 = expf(s4s[3] - mx);
        float inv = 1.f / (e0 + e1 + e2 + e3);
        swl[0] = e0 * inv; swl[1] = e1 * inv; swl[2] = e2 * inv; swl[3] = e3 * inv;
        for (int o = 0; o < 4; o++) sw_out[b * 4 + o] = swl[o];
    }
    __syncthreads();
    if (t < 256)
        beff[b * 256 + t] = swl[0] * lb0[t] + swl[1] * lb1[t] + swl[2] * lb2[t] + swl[3] * lb3[t];
    // hoisted: ldot[l][pair] = dot(lemb[l], Wa[pair]); block b handles l = 10b..10b+9
    {
        int pair = t >> 6;
        #pragma unroll
        for (int r = 0; r < 10; r++) {
            int l = b * 10 + r;
            const float* le = lemb + l * 256 + lane * 4;
            const float* wa = Wa + pair * 256 + lane * 4;
            float p = le[0] * wa[0] + le[1] * wa[1] + le[2] * wa[2] + le[3] * wa[3];
            #pragma unroll
            for (int off = 32; off > 0; off >>= 1) p += __shfl_xor(p, off, 64);
            if (lane == 0) ldot[l * 8 + pair] = p;
        }
    }
}

// -------- K3: lateral projection, FULL K=3840 per block (no atomics), bias fused --------
__global__ __launch_bounds__(256) void lateral_full(
    const float* __restrict__ pf0, const float* __restrict__ pf1,
    const float* __restrict__ pf2, const float* __restrict__ pf3,
    const float* __restrict__ w0, const float* __restrict__ w1,
    const float* __restrict__ w2, const float* __restrict__ w3,
    const float* __restrict__ sw, const float* __restrict__ beff,
    float* __restrict__ xtok)
{
    int mt = blockIdx.x % 49, nt = blockIdx.x / 49;
    int m0 = mt * 32, n0 = nt * 64;
    __shared__ alignas(16) unsigned short As[1024];
    __shared__ alignas(16) unsigned short Bs[2048];
    int t = threadIdx.x, lane = t & 63, wid = t >> 6;
    int wm = wid >> 1, wn = wid & 1;
    f32x4 acc0 = {0, 0, 0, 0}, acc1 = {0, 0, 0, 0};

    int f = t & 63;
    int mA = m0 + ((t >> 6) & 1) * 16 + (f & 15);   // t<128
    int kbA = (f >> 4) * 8;
    int nB = n0 + (t >> 6) * 16 + (f & 15);
    int kbB = (f >> 4) * 8;
    int bA = mA / 196;

    float ar[8], br[8];
    // scale boundaries at k = 256, 768, 1792 (all multiples of 32)
    auto loadA = [&](int k0) {
        if (t < 128) {
            int kb = k0 + kbA;
            int s, rel;
            if (kb < 256)       { s = 0; rel = kb; }
            else if (kb < 768)  { s = 1; rel = kb - 256; }
            else if (kb < 1792) { s = 2; rel = kb - 768; }
            else                { s = 3; rel = kb - 1792; }
            const float* pf = (s == 0) ? pf0 : (s == 1) ? pf1 : (s == 2) ? pf2 : pf3;
            float swv = sw[bA * 4 + s];
            const float* base = pf + (size_t)rel * 1568 + mA;
            #pragma unroll
            for (int j = 0; j < 8; j++) ar[j] = base[(size_t)j * 1568] * swv;
        }
    };
    auto loadB = [&](int k0) {
        int kb = k0 + kbB;
        int s, rel;
        if (kb < 256)       { s = 0; rel = kb; }
        else if (kb < 768)  { s = 1; rel = kb - 256; }
        else if (kb < 1792) { s = 2; rel = kb - 768; }
        else                { s = 3; rel = kb - 1792; }
        const float* W = (s == 0) ? w0 : (s == 1) ? w1 : (s == 2) ? w2 : w3;
        const float* base = W + (size_t)rel * 256 + nB;
        #pragma unroll
        for (int j = 0; j < 8; j++) br[j] = base[(size_t)j * 256];
    };

    loadA(0); loadB(0);
    for (int k0 = 0; k0 < 3840; k0 += 32) {
        if (t < 128) *(bshort8*)&As[(((t >> 6) & 1) * 512 + f * 8)] = pack8(ar);
        *(bshort8*)&Bs[((t >> 6) * 512 + f * 8)] = pack8(br);
        __syncthreads();
        if (k0 + 32 < 3840) { loadA(k0 + 32); loadB(k0 + 32); }
        bshort8 av = *(const bshort8*)&As[wm * 512 + lane * 8];
        bshort8 bv0 = *(const bshort8*)&Bs[(wn * 2 + 0) * 512 + lane * 8];
        bshort8 bv1 = *(const bshort8*)&Bs[(wn * 2 + 1) * 512 + lane * 8];
        acc0 = mfma16(av, bv0, acc0);
        acc1 = mfma16(av, bv1, acc1);
        __syncthreads();
    }
    int col0 = n0 + wn * 32 + (lane & 15);
    int rbase = m0 + wm * 16 + ((lane >> 4) << 2);
    #pragma unroll
    for (int r = 0; r < 4; r++) {
        int m = rbase + r;
        int bC = m / 196;
        xtok[(size_t)m * 256 + col0]      = acc0[r] + beff[bC * 256 + col0];
        xtok[(size_t)m * 256 + col0 + 16] = acc1[r] + beff[bC * 256 + col0 + 16];
    }
}

// -------- generic bf16-MFMA GEMM --------
template <bool B_IS_KXN>
__global__ __launch_bounds__(256) void gemm_kernel(
    const float* __restrict__ Ab, int lda, long long sAy, long long sAz,
    const float* __restrict__ Bb, int ldb, long long sBy, long long sBz,
    float* __restrict__ Cb, int ldc, long long sCy, long long sCz,
    const float* __restrict__ bias, int M, int N, int K,
    float alpha, int mtiles)
{
    const float* A = Ab + blockIdx.y * sAy + blockIdx.z * sAz;
    const float* B = Bb + blockIdx.y * sBy + blockIdx.z * sBz;
    float* C = Cb + blockIdx.y * sCy + blockIdx.z * sCz;
    int mt = blockIdx.x % mtiles, nt = blockIdx.x / mtiles;
    int m0 = mt * 32, n0 = nt * 64;
    __shared__ alignas(16) unsigned short As[1024];
    __shared__ alignas(16) unsigned short Bs[2048];
    int t = threadIdx.x, lane = t & 63, wid = t >> 6;
    int wm = wid >> 1, wn = wid & 1;
    f32x4 acc0 = {0, 0, 0, 0}, acc1 = {0, 0, 0, 0};

    int f = t & 63;
    int mA = m0 + ((t >> 6) & 1) * 16 + (f & 15);   // t<128
    int kbA = (f >> 4) * 8;
    int nB = n0 + (t >> 6) * 16 + (f & 15);
    int kbB = (f >> 4) * 8;

    float ar[8], br[8];
    auto loadA = [&](int k0) {
        if (t < 128) {
            int kb = k0 + kbA;
            if (mA < M && kb + 8 <= K) {
                const float4* p = (const float4*)(A + (size_t)mA * lda + kb);
                float4 u = p[0], v = p[1];
                ar[0] = u.x; ar[1] = u.y; ar[2] = u.z; ar[3] = u.w;
                ar[4] = v.x; ar[5] = v.y; ar[6] = v.z; ar[7] = v.w;
            } else {
                #pragma unroll
                for (int j = 0; j < 8; j++) {
                    int k = kb + j;
                    ar[j] = (mA < M && k < K) ? A[(size_t)mA * lda + k] : 0.f;
                }
            }
        }
    };
    auto loadB = [&](int k0) {
        int kb = k0 + kbB;
        if constexpr (B_IS_KXN) {
            #pragma unroll
            for (int j = 0; j < 8; j++) {
                int k = kb + j;
                br[j] = (k < K && nB < N) ? B[(size_t)k * ldb + nB] : 0.f;
            }
        } else {
            if (nB < N && kb + 8 <= K) {
                const float4* p = (const float4*)(B + (size_t)nB * ldb + kb);
                float4 u = p[0], v = p[1];
                br[0] = u.x; br[1] = u.y; br[2] = u.z; br[3] = u.w;
                br[4] = v.x; br[5] = v.y; br[6] = v.z; br[7] = v.w;
            } else {
                #pragma unroll
                for (int j = 0; j < 8; j++) {
                    int k = kb + j;
                    br[j] = (nB < N && k < K) ? B[(size_t)nB * ldb + k] : 0.f;
                }
            }
        }
    };

    loadA(0); loadB(0);
    for (int k0 = 0; k0 < K; k0 += 32) {
        if (t < 128) *(bshort8*)&As[(((t >> 6) & 1) * 512 + f * 8)] = pack8(ar);
        *(bshort8*)&Bs[((t >> 6) * 512 + f * 8)] = pack8(br);
        __syncthreads();
        if (k0 + 32 < K) { loadA(k0 + 32); loadB(k0 + 32); }
        bshort8 av = *(const bshort8*)&As[wm * 512 + lane * 8];
        bshort8 bv0 = *(const bshort8*)&Bs[(wn * 2 + 0) * 512 + lane * 8];
        bshort8 bv1 = *(const bshort8*)&Bs[(wn * 2 + 1) * 512 + lane * 8];
        acc0 = mfma16(av, bv0, acc0);
        acc1 = mfma16(av, bv1, acc1);
        __syncthreads();
    }
    int col0 = n0 + wn * 32 + (lane & 15);
    int rbase = m0 + wm * 16 + ((lane >> 4) << 2);
    #pragma unroll
    for (int r = 0; r < 4; r++) {
        int m = rbase + r;
        if (m < M) {
            if (col0 < N) {
                float v = acc0[r] * alpha;
                if (bias) v += bias[col0];
                C[(size_t)m * ldc + col0] = v;
            }
            int c1 = col0 + 16;
            if (c1 < N) {
                float v = acc1[r] * alpha;
                if (bias) v += bias[c1];
                C[(size_t)m * ldc + c1] = v;
            }
        }
    }
}

// -------- attention softmax over rows of S [12544][196], in place --------
__global__ __launch_bounds__(256) void attn_softmax(float* __restrict__ S)
{
    int wid = threadIdx.x >> 6, lane = threadIdx.x & 63;
    size_t row = (size_t)blockIdx.x * 4 + wid;
    float* p = S + row * 196;
    float v0 = p[lane];
    float v1 = p[64 + lane];
    float v2 = p[128 + lane];
    float v3 = (lane < 4) ? p[192 + lane] : -1e30f;
    float mx = fmaxf(fmaxf(v0, v1), fmaxf(v2, v3));
    #pragma unroll
    for (int off = 32; off > 0; off >>= 1) mx = fmaxf(mx, __shfl_xor(mx, off, 64));
    float e0 = expf(v0 - mx), e1 = expf(v1 - mx), e2 = expf(v2 - mx);
    float e3 = (lane < 4) ? expf(v3 - mx) : 0.f;
    float sum = e0 + e1 + e2 + e3;
    #pragma unroll
    for (int off = 32; off > 0; off >>= 1) sum += __shfl_xor(sum, off, 64);
    float inv = 1.f / sum;
    p[lane] = e0 * inv;
    p[64 + lane] = e1 * inv;
    p[128 + lane] = e2 * inv;
    if (lane < 4) p[192 + lane] = e3 * inv;
}

// ================= tail: ONE block (1024 threads) per batch element =================
// All sync is __syncthreads(); all intermediates in LDS. No device-scope fences.
// Key algebra: col-mean am of a row-softmax matrix sums to 1, so
//   av[h][c] = (sum_l am_raw[h][l]*lemb[l][c])/80 + gctx[c]   (lf never materialized)
// and s12[pair][l] = ldot[l][pair] + dot(gctx, Wa[pair])      (ldot hoisted to sw_fin)
__global__ __launch_bounds__(1024) void tail_block(
    const float* __restrict__ xo, const float* __restrict__ proj_w,
    const float* __restrict__ proj_b,
    const float* __restrict__ gat_W, const float* __restrict__ lemb,
    const float* __restrict__ out_w, const float* __restrict__ out_b,
    const float* __restrict__ spec_w1, const float* __restrict__ spec_b1,
    const float* __restrict__ spec_w2, const float* __restrict__ spec_b2,
    const float* __restrict__ spat_w1, const float* __restrict__ spat_b1,
    const float* __restrict__ spat_w2, const float* __restrict__ spat_b2,
    const float* __restrict__ gate_w, const float* __restrict__ gate_b,
    const float* __restrict__ unc_w, const float* __restrict__ unc_b,
    const float* __restrict__ Wa, const float* __restrict__ ldot,
    float* __restrict__ atts, float* __restrict__ out)
{
    int b = blockIdx.x, t = threadIdx.x;
    int lane = t & 63, wv = t >> 6;
    __shared__ float red[1024];
    __shared__ float xm[256];
    __shared__ float gctx_s[256];
    __shared__ float gdot_s[8];
    __shared__ float s12_s[640];
    __shared__ float am_s[320];
    __shared__ float av_s[1024];
    __shared__ float hm_s[1024];
    __shared__ float as_s[256];
    __shared__ float hb_s[256];
    __shared__ float fv_s[320];

    // ---- P0: xm = token-mean of xo[b] ----
    {
        int c = t & 255, sl = t >> 8;
        const float* base = xo + ((size_t)b * 196 + sl * 49) * 256 + c;
        float s = 0.f;
        #pragma unroll 7
        for (int i = 0; i < 49; i++) s += base[(size_t)i * 256];
        red[t] = s;
    }
    __syncthreads();
    if (t < 256) xm[t] = (red[t] + red[256 + t] + red[512 + t] + red[768 + t]) * (1.f / 196.f);
    __syncthreads();

    // ---- P1: gctx = xm @ proj_w + proj_b ----
    {
        int n = t & 255, ks = t >> 8;
        float acc = 0.f;
        const float* w = proj_w + (size_t)(ks * 64) * 256 + n;
        #pragma unroll 8
        for (int i = 0; i < 64; i++) acc += xm[ks * 64 + i] * w[(size_t)i * 256];
        red[t] = acc;
    }
    if (t < 320) am_s[t] = 0.f;
    __syncthreads();
    if (t < 256) gctx_s[t] = proj_b[t] + red[t] + red[256 + t] + red[512 + t] + red[768 + t];
    __syncthreads();

    // ---- P2: gdot[pair] = dot(gctx, Wa[pair]);  s12 = ldot + gdot ----
    if (wv < 8) {
        const float* wa = Wa + wv * 256 + lane * 4;
        float p = gctx_s[lane * 4] * wa[0] + gctx_s[lane * 4 + 1] * wa[1]
                + gctx_s[lane * 4 + 2] * wa[2] + gctx_s[lane * 4 + 3] * wa[3];
        #pragma unroll
        for (int off = 32; off > 0; off >>= 1) p += __shfl_xor(p, off, 64);
        if (lane == 0) gdot_s[wv] = p;
    }
    __syncthreads();
    if (t < 640) {
        int pair = t / 80, l = t - pair * 80;
        s12_s[t] = ldot[l * 8 + pair] + gdot_s[pair];
    }
    __syncthreads();

    // ---- P3: GAT row softmax -> atts (+ LDS am accumulation) ----
    {
        #pragma unroll
        for (int rr = 0; rr < 20; rr++) {
            int row = rr * 16 + wv;
            int h = row / 80, i = row - h * 80;
            float s1i = s12_s[(h * 2) * 80 + i];
            const float* s2 = s12_s + (h * 2 + 1) * 80;
            float v0 = s1i + s2[lane]; v0 = v0 > 0.f ? v0 : 0.2f * v0;
            float v1 = -1e30f;
            if (lane < 16) { v1 = s1i + s2[64 + lane]; v1 = v1 > 0.f ? v1 : 0.2f * v1; }
            float mx = fmaxf(v0, v1);
            #pragma unroll
            for (int off = 32; off > 0; off >>= 1) mx = fmaxf(mx, __shfl_xor(mx, off, 64));
            float e0 = expf(v0 - mx), e1 = (lane < 16) ? expf(v1 - mx) : 0.f;
            float sum = e0 + e1;
            #pragma unroll
            for (int off = 32; off > 0; off >>= 1) sum += __shfl_xor(sum, off, 64);
            float inv = 1.f / sum;
            float* orow = atts + (size_t)h * 51200 + b * 6400 + i * 80;
            float p0 = e0 * inv;
            orow[lane] = p0;
            atomicAdd(&am_s[h * 80 + lane], p0);
            if (lane < 16) {
                float p1 = e1 * inv;
                orow[64 + lane] = p1;
                atomicAdd(&am_s[h * 80 + 64 + lane], p1);
            }
        }
    }
    __syncthreads();

    // ---- P4: av[h][c] = (am_raw[h] . lemb[:,c])/80 + gctx[c]; hm[h] = av[h] @ gat_W[h] ----
    {
        int h = t >> 8, c = t & 255;
        float acc = 0.f;
        const float* le = lemb + c;
        const float* amh = am_s + h * 80;
        #pragma unroll 8
        for (int l = 0; l < 80; l++) acc += amh[l] * le[(size_t)l * 256];
        av_s[t] = acc * (1.f / 80.f) + gctx_s[c];
    }
    __syncthreads();
    {
        int h = t >> 8, n = t & 255;
        float acc = 0.f;
        const float* w = gat_W + (size_t)h * 65536 + n;
        const float* av = av_s + h * 256;
        #pragma unroll 8
        for (int k = 0; k < 256; k++) acc += av[k] * w[(size_t)k * 256];
        hm_s[t] = acc;
    }
    __syncthreads();

    // ---- P5: a_s = concat(hm) @ out_w + out_b ----
    {
        int n = t & 255, ks = t >> 8;
        float acc = 0.f;
        const float* w = out_w + (size_t)(ks * 256) * 256 + n;
        const float* hv = hm_s + ks * 256;
        #pragma unroll 8
        for (int k = 0; k < 256; k++) acc += hv[k] * w[(size_t)k * 256];
        red[t] = acc;
    }
    __syncthreads();
    if (t < 256) as_s[t] = out_b[t] + red[t] + red[256 + t] + red[512 + t] + red[768 + t];
    __syncthreads();

    // ---- P6: hidden = relu(a_s @ w1 + b1) for spec (u<128) and spat (u>=128) ----
    {
        int u = t & 255, ks = t >> 8;
        int which = u >> 7, oo = u & 127;
        const float* w1 = which ? spat_w1 : spec_w1;
        float acc = 0.f;
        #pragma unroll 8
        for (int i = 0; i < 64; i++) {
            int k = ks * 64 + i;
            acc += as_s[k] * w1[(size_t)k * 128 + oo];
        }
        red[t] = acc;
    }
    __syncthreads();
    if (t < 256) {
        int which = t >> 7, oo = t & 127;
        const float* b1 = which ? spat_b1 : spec_b1;
        hb_s[t] = fmaxf(red[t] + red[256 + t] + red[512 + t] + red[768 + t] + b1[oo], 0.f);
    }
    __syncthreads();

    // ---- P7: head pre-activations fv[head][80], 3-way split-K ----
    if (t < 960) {
        int sub = t / 320, u = t - sub * 320;
        int head = u / 80, o = u - head * 80;
        const float* wp; const float* src; int K;
        if (head == 0)      { wp = spec_w2; src = hb_s;       K = 128; }
        else if (head == 1) { wp = spat_w2; src = hb_s + 128; K = 128; }
        else if (head == 2) { wp = gate_w;  src = as_s;       K = 256; }
        else                { wp = unc_w;   src = as_s;       K = 256; }
        int k0 = (K * sub) / 3, k1 = (K * (sub + 1)) / 3;
        float acc = 0.f;
        for (int k = k0; k < k1; k++) acc += src[k] * wp[(size_t)k * 80 + o];
        red[sub * 320 + u] = acc;
    }
    __syncthreads();
    if (t < 320) {
        int head = t / 80, o = t - head * 80;
        const float* bp = head == 0 ? spec_b2 : head == 1 ? spat_b2 : head == 2 ? gate_b : unc_b;
        fv_s[t] = red[t] + red[320 + t] + red[640 + t] + bp[o];
    }
    __syncthreads();

    // ---- P8: final combine ----
    if (t < 80) {
        float sp = fv_s[t], st2 = fv_s[80 + t], gz = fv_s[160 + t], uz = fv_s[240 + t];
        float g = 1.f / (1.f + expf(-gz));
        out[b * 80 + t] = g * sp + (1.f - g) * st2;
        out[640 + b * 80 + t] = sp;
        out[1280 + b * 80 + t] = st2;
        out[1920 + b * 80 + t] = g;
        red[t] = log1pf(expf(uz)) + 1.f;
    }
    __syncthreads();
    if (t == 0) {
        float s = 0.f;
        for (int l = 0; l < 80; l++) s += red[l];
        out[2560 + b] = 80.f / s;
    }
}

// ---------------- launcher ----------------
extern "C" void kernel_launch(void* const* d_in, const int* in_sizes, int n_in,
                              void* d_out, int out_size, void* d_ws, size_t ws_size,
                              hipStream_t stream)
{
    (void)in_sizes; (void)n_in; (void)out_size; (void)ws_size;
    const float* c2 = (const float*)d_in[0];
    const float* c3 = (const float*)d_in[1];
    const float* c4 = (const float*)d_in[2];
    const float* c5 = (const float*)d_in[3];
    const float* lat_w0 = (const float*)d_in[4];
    const float* lat_b0 = (const float*)d_in[5];
    const float* lat_w1 = (const float*)d_in[6];
    const float* lat_b1 = (const float*)d_in[7];
    const float* lat_w2 = (const float*)d_in[8];
    const float* lat_b2 = (const float*)d_in[9];
    const float* lat_w3 = (const float*)d_in[10];
    const float* lat_b3 = (const float*)d_in[11];
    const float* sp_w1 = (const float*)d_in[12];
    const float* sp_b1 = (const float*)d_in[13];
    const float* sp_w2 = (const float*)d_in[14];
    const float* sp_b2 = (const float*)d_in[15];
    const float* qkv_w = (const float*)d_in[16];
    const float* qkv_b = (const float*)d_in[17];
    const float* proj_w = (const float*)d_in[18];
    const float* proj_b = (const float*)d_in[19];
    const float* gat_W = (const float*)d_in[20];
    const float* gat_a = (const float*)d_in[21];
    const float* out_w = (const float*)d_in[22];
    const float* out_b = (const float*)d_in[23];
    const float* label_emb = (const float*)d_in[24];
    const float* spec_w1 = (const float*)d_in[25];
    const float* spec_b1 = (const float*)d_in[26];
    const float* spec_w2 = (const float*)d_in[27];
    const float* spec_b2 = (const float*)d_in[28];
    const float* spat_w1 = (const float*)d_in[29];
    const float* spat_b1 = (const float*)d_in[30];
    const float* spat_w2 = (const float*)d_in[31];
    const float* spat_b2 = (const float*)d_in[32];
    const float* gate_w = (const float*)d_in[33];
    const float* gate_b = (const float*)d_in[34];
    const float* unc_w = (const float*)d_in[35];
    const float* unc_b = (const float*)d_in[36];

    float* out = (float*)d_out;
    float* ws = (float*)d_ws;

    // workspace layout (floats); later phases reuse dead regions
    float* pf0    = ws + 0;        // 401408
    float* pf1    = ws + 401408;
    float* pf2    = ws + 1204224;
    float* pf3    = ws + 2809856;  // ends 6021120
    float* pooled = ws + 6021120;  // 16384  -> 6037504
    float* beff   = ws + 6037504;  // 2048   -> 6039552
    float* swpart = ws + 6039552;  // 32768  -> 6072320
    float* Wa     = ws + 6072320;  // 2048   -> 6074368
    float* ldot   = ws + 6074368;  // 640    -> 6075008
    float* qkv    = ws + 0;        // reuses pf0/pf1 (dead after lateral)
    float* S      = ws + 1204224;  // reuses pf2/pf3 (dead after lateral)
    float* xo     = ws + 3662848;  // 401408 -> 4064256
    float* xtok   = ws + 6106112;  // 401408 -> 6507520

    float* swp  = out + 2568;  // sw [8,4] (output 5)
    float* atts = out + 2600;  // atts [4,8,80,80] (output 6)

    // 1. ALL pools + c5 mean in one dispatch
    pool_all<<<27616, 256, 0, stream>>>(c2, c3, c4, c5, pf0, pf1, pf2, pf3, pooled);
    // 2. scale-weight MLP partials + hoisted Wa (16 extra blocks)
    sw_part<<<dim3(8, 10), 512, 0, stream>>>(pooled, sp_w1, swpart, gat_W, gat_a, Wa);
    // 2b. finish sw MLP (sw + beff) + hoisted ldot = lemb @ Wa^T
    sw_fin<<<8, 512, 0, stream>>>(swpart, sp_b1, sp_w2, sp_b2,
                                  lat_b0, lat_b1, lat_b2, lat_b3,
                                  label_emb, Wa, swp, beff, ldot);
    // 3. lateral projection, full-K per block, bias fused -> xtok [1568,256]
    lateral_full<<<196, 256, 0, stream>>>(pf0, pf1, pf2, pf3,
                                          lat_w0, lat_w1, lat_w2, lat_w3,
                                          swp, beff, xtok);
    // 4. qkv = x @ qkv_w + qkv_b : [1568,768]
    gemm_kernel<true><<<dim3(49 * 12, 1, 1), 256, 0, stream>>>(
        xtok, 256, 0, 0, qkv_w, 768, 0, 0, qkv, 768, 0, 0,
        qkv_b, 1568, 768, 256, 1.f, 49);
    // 5. S = q @ k^T * hd^-0.5, per (b,h) : [64,196,196]
    gemm_kernel<false><<<dim3(7 * 4, 8, 8), 256, 0, stream>>>(
        qkv, 768, 150528, 32, qkv + 256, 768, 150528, 32,
        S, 196, 307328, 38416, nullptr, 196, 196, 32, 0.17677669529663687f, 7);
    // 6. row softmax on S (in place)
    attn_softmax<<<3136, 256, 0, stream>>>(S);
    // 7. xo = P @ v : [1568,256] (head-concat layout)
    gemm_kernel<true><<<dim3(7, 8, 8), 256, 0, stream>>>(
        S, 196, 307328, 38416, qkv + 512, 768, 150528, 32,
        xo, 256, 50176, 32, nullptr, 196, 32, 196, 1.f, 7);
    // 8. entire tail: one 1024-thread block per batch element, LDS-only sync
    tail_block<<<8, 1024, 0, stream>>>(
        xo, proj_w, proj_b, gat_W, label_emb, out_w, out_b,
        spec_w1, spec_b1, spec_w2, spec_b2,
        spat_w1, spat_b1, spat_w2, spat_b2,
        gate_w, gate_b, unc_w, unc_b,
        Wa, ldot, atts, out);
}

// Round 5
// 507.221 us; speedup vs baseline: 1.3028x; 1.3028x over previous
//
#include <hip/hip_runtime.h>
#include <math.h>

typedef __attribute__((ext_vector_type(8))) short bshort8;
typedef __attribute__((ext_vector_type(4))) float f32x4;

#define DI __device__ __forceinline__

DI unsigned short f2bf(float x) {
    unsigned int u = __builtin_bit_cast(unsigned int, x);
    u += 0x7fffu + ((u >> 16) & 1u);
    return (unsigned short)(u >> 16);
}

DI bshort8 pack8(const float* v) {
    bshort8 r;
    #pragma unroll
    for (int j = 0; j < 8; j++) r[j] = (short)f2bf(v[j]);
    return r;
}

DI f32x4 mfma16(bshort8 a, bshort8 b, f32x4 c) {
    return __builtin_amdgcn_mfma_f32_16x16x32_bf16(a, b, c, 0, 0, 0);
}

// ---- composite (bilinear resize N->112, align_corners=False) + 8x8 avgpool stencils ----
__device__ const float W14[14][3] = {
    {0.875f, 0.125f, 0.f},
    {0.125f, 0.75f, 0.125f}, {0.125f, 0.75f, 0.125f}, {0.125f, 0.75f, 0.125f},
    {0.125f, 0.75f, 0.125f}, {0.125f, 0.75f, 0.125f}, {0.125f, 0.75f, 0.125f},
    {0.125f, 0.75f, 0.125f}, {0.125f, 0.75f, 0.125f}, {0.125f, 0.75f, 0.125f},
    {0.125f, 0.75f, 0.125f}, {0.125f, 0.75f, 0.125f}, {0.125f, 0.75f, 0.125f},
    {0.125f, 0.875f, 0.f}};
__device__ const float W28[14][4] = {
    {0.5f, 0.4375f, 0.0625f, 0.f},
    {0.0625f, 0.4375f, 0.4375f, 0.0625f}, {0.0625f, 0.4375f, 0.4375f, 0.0625f},
    {0.0625f, 0.4375f, 0.4375f, 0.0625f}, {0.0625f, 0.4375f, 0.4375f, 0.0625f},
    {0.0625f, 0.4375f, 0.4375f, 0.0625f}, {0.0625f, 0.4375f, 0.4375f, 0.0625f},
    {0.0625f, 0.4375f, 0.4375f, 0.0625f}, {0.0625f, 0.4375f, 0.4375f, 0.0625f},
    {0.0625f, 0.4375f, 0.4375f, 0.0625f}, {0.0625f, 0.4375f, 0.4375f, 0.0625f},
    {0.0625f, 0.4375f, 0.4375f, 0.0625f}, {0.0625f, 0.4375f, 0.4375f, 0.0625f},
    {0.0625f, 0.4375f, 0.5f, 0.f}};
__device__ const float W56[14][6] = {
    {0.25f, 0.25f, 0.25f, 0.21875f, 0.03125f, 0.f},
    {0.03125f, 0.21875f, 0.25f, 0.25f, 0.21875f, 0.03125f},
    {0.03125f, 0.21875f, 0.25f, 0.25f, 0.21875f, 0.03125f},
    {0.03125f, 0.21875f, 0.25f, 0.25f, 0.21875f, 0.03125f},
    {0.03125f, 0.21875f, 0.25f, 0.25f, 0.21875f, 0.03125f},
    {0.03125f, 0.21875f, 0.25f, 0.25f, 0.21875f, 0.03125f},
    {0.03125f, 0.21875f, 0.25f, 0.25f, 0.21875f, 0.03125f},
    {0.03125f, 0.21875f, 0.25f, 0.25f, 0.21875f, 0.03125f},
    {0.03125f, 0.21875f, 0.25f, 0.25f, 0.21875f, 0.03125f},
    {0.03125f, 0.21875f, 0.25f, 0.25f, 0.21875f, 0.03125f},
    {0.03125f, 0.21875f, 0.25f, 0.25f, 0.21875f, 0.03125f},
    {0.03125f, 0.21875f, 0.25f, 0.25f, 0.21875f, 0.03125f},
    {0.03125f, 0.21875f, 0.25f, 0.25f, 0.21875f, 0.03125f},
    {0.03125f, 0.21875f, 0.25f, 0.25f, 0.25f, 0.f}};

// -------- pooled-feature bodies; pf layout [cin][1568], col = b*196 + r --------
template <int N, int C, int TAPS>
DI void pool_body(const float* __restrict__ src, float* __restrict__ dst,
                  unsigned blk, unsigned t)
{
    unsigned id = blk * 256u + t;
    unsigned p = id / 196u;
    unsigned r = id - p * 196u;
    unsigned ti = r / 14u, tj = r - ti * 14u;
    unsigned b = p / C, cin = p - b * C;
    const float* plane = src + (size_t)p * (N * N);
    float acc = 0.f;
    if constexpr (N == 112) {
        const float4* p4 = (const float4*)(plane + (size_t)(ti * 8) * 112 + tj * 8);
        #pragma unroll
        for (int i = 0; i < 8; i++) {
            float4 u = p4[i * 28];
            float4 v = p4[i * 28 + 1];
            acc += (u.x + u.y) + (u.z + u.w) + (v.x + v.y) + (v.z + v.w);
        }
        acc *= (1.f / 64.f);
    } else {
        constexpr int STRIDE = N / 14;
        const float (*WT)[TAPS] = (N == 14) ? (const float (*)[TAPS])W14
                                : (N == 28) ? (const float (*)[TAPS])W28
                                            : (const float (*)[TAPS])W56;
        int hs = (int)(STRIDE * ti) - 1; if (hs < 0) hs = 0;
        int ws = (int)(STRIDE * tj) - 1; if (ws < 0) ws = 0;
        float wh[TAPS], ww[TAPS];
        #pragma unroll
        for (int i = 0; i < TAPS; i++) { wh[i] = WT[ti][i]; ww[i] = WT[tj][i]; }
        #pragma unroll
        for (int i = 0; i < TAPS; i++) {
            int hi = hs + i; if (hi > N - 1) hi = N - 1;
            const float* row = plane + (size_t)hi * N;
            float rs = 0.f;
            #pragma unroll
            for (int j = 0; j < TAPS; j++) {
                int wj = ws + j; if (wj > N - 1) wj = N - 1;
                rs += ww[j] * row[wj];
            }
            acc += wh[i] * rs;
        }
    }
    dst[(size_t)cin * 1568 + b * 196 + r] = acc;
}

DI void c5_mean_body(const float* __restrict__ c5, float* __restrict__ pooled,
                     unsigned blk, unsigned t)
{
    int wid = t >> 6, lane = t & 63;
    int p = blk * 4 + wid;
    const float* plane = c5 + (size_t)p * 196;
    float v = plane[lane] + plane[64 + lane] + plane[128 + lane];
    if (lane < 4) v += plane[192 + lane];
    #pragma unroll
    for (int off = 32; off > 0; off >>= 1) v += __shfl_xor(v, off, 64);
    if (lane == 0) pooled[p] = v * (1.f / 196.f);
}

// -------- K1: all four scale pools + c5 mean in ONE dispatch --------
__global__ __launch_bounds__(256) void pool_all(
    const float* __restrict__ c2, const float* __restrict__ c3,
    const float* __restrict__ c4, const float* __restrict__ c5,
    float* __restrict__ pf0, float* __restrict__ pf1,
    float* __restrict__ pf2, float* __restrict__ pf3,
    float* __restrict__ pooled)
{
    unsigned bx = blockIdx.x, t = threadIdx.x;
    if (bx < 1568u)       pool_body<112, 256, 8>(c2, pf0, bx, t);
    else if (bx < 4704u)  pool_body<56, 512, 6>(c3, pf1, bx - 1568u, t);
    else if (bx < 10976u) pool_body<28, 1024, 4>(c4, pf2, bx - 4704u, t);
    else if (bx < 23520u) pool_body<14, 2048, 3>(c5, pf3, bx - 10976u, t);
    else                  c5_mean_body(c5, pooled, bx - 23520u, t);
}

// -------- K2a: partial GEMV for sw MLP layer 1 (split-K) + hoisted Wa (y>=8) --------
__global__ __launch_bounds__(512) void sw_part(
    const float* __restrict__ pooled, const float* __restrict__ sp_w1,
    float* __restrict__ partial,
    const float* __restrict__ gat_W, const float* __restrict__ gat_a,
    float* __restrict__ Wa)
{
    int t = threadIdx.x;
    if (blockIdx.y >= 8) {
        // Wa[h][which][c] = dot(gat_W[h][c][:], a_which); 16 blocks, one (h,q) each
        int e = (blockIdx.y - 8) * 8 + blockIdx.x;   // [0,16)
        int h = e >> 2, q = e & 3;
        __shared__ float a1[256], a2[256];
        if (t < 256) { a1[t] = gat_a[h * 512 + t]; a2[t] = gat_a[h * 512 + 256 + t]; }
        __syncthreads();
        int w = t >> 6, lane = t & 63;
        #pragma unroll
        for (int ci = 0; ci < 8; ci++) {
            int c = q * 64 + w * 8 + ci;
            const float* row = gat_W + (size_t)h * 65536 + (size_t)c * 256;
            float p1 = 0.f, p2 = 0.f;
            #pragma unroll
            for (int jj = 0; jj < 4; jj++) {
                float v = row[lane + 64 * jj];
                p1 += v * a1[lane + 64 * jj];
                p2 += v * a2[lane + 64 * jj];
            }
            #pragma unroll
            for (int off = 32; off > 0; off >>= 1) {
                p1 += __shfl_xor(p1, off, 64);
                p2 += __shfl_xor(p2, off, 64);
            }
            if (lane == 0) { Wa[h * 512 + c] = p1; Wa[h * 512 + 256 + c] = p2; }
        }
        return;
    }
    int b = blockIdx.x, kc = blockIdx.y;
    __shared__ float ps[256];
    if (t < 256) ps[t] = pooled[b * 2048 + kc * 256 + t];
    __syncthreads();
    float acc = 0.f;
    const float* w = sp_w1 + (size_t)(kc * 256) * 512 + t;
    #pragma unroll 8
    for (int c = 0; c < 256; c++) acc += ps[c] * w[(size_t)c * 512];
    partial[((size_t)b * 8 + kc) * 512 + t] = acc;
}

// -------- K2b: finish sw MLP + bias-init xtok + hoisted ldot = lemb @ Wa^T --------
__global__ __launch_bounds__(512) void sw_fin(
    const float* __restrict__ partial, const float* __restrict__ sp_b1,
    const float* __restrict__ sp_w2, const float* __restrict__ sp_b2,
    const float* __restrict__ lb0, const float* __restrict__ lb1,
    const float* __restrict__ lb2, const float* __restrict__ lb3,
    const float* __restrict__ lemb, const float* __restrict__ Wa,
    float* __restrict__ sw_out, float* __restrict__ xtok,
    float* __restrict__ ldot)
{
    int b = blockIdx.x, t = threadIdx.x;
    __shared__ float h[512];
    __shared__ float s4s[4];
    __shared__ float swl[4];
    __shared__ float bf_s[256];
    float a = sp_b1[t];
    #pragma unroll
    for (int kc = 0; kc < 8; kc++) a += partial[((size_t)b * 8 + kc) * 512 + t];
    h[t] = fmaxf(a, 0.f);
    __syncthreads();
    int wv = t >> 6, lane = t & 63;
    if (wv < 4) {
        float acc = 0.f;
        #pragma unroll
        for (int i = 0; i < 8; i++) {
            int idx = lane + 64 * i;
            acc += h[idx] * sp_w2[idx * 4 + wv];
        }
        #pragma unroll
        for (int off = 32; off > 0; off >>= 1) acc += __shfl_xor(acc, off, 64);
        if (lane == 0) s4s[wv] = acc + sp_b2[wv];
    }
    __syncthreads();
    if (t == 0) {
        float mx = fmaxf(fmaxf(s4s[0], s4s[1]), fmaxf(s4s[2], s4s[3]));
        float e0 = expf(s4s[0] - mx), e1 = expf(s4s[1] - mx);
        float e2 = expf(s4s[2] - mx), e3 = expf(s4s[3] - mx);
        float inv = 1.f / (e0 + e1 + e2 + e3);
        swl[0] = e0 * inv; swl[1] = e1 * inv; swl[2] = e2 * inv; swl[3] = e3 * inv;
        for (int o = 0; o < 4; o++) sw_out[b * 4 + o] = swl[o];
    }
    __syncthreads();
    if (t < 256)
        bf_s[t] = swl[0] * lb0[t] + swl[1] * lb1[t] + swl[2] * lb2[t] + swl[3] * lb3[t];
    // hoisted: ldot[l][pair] = dot(lemb[l], Wa[pair]); block b handles l = 10b..10b+9
    {
        int pair = t >> 6;
        #pragma unroll
        for (int r = 0; r < 10; r++) {
            int l = b * 10 + r;
            const float* le = lemb + l * 256 + lane * 4;
            const float* wa = Wa + pair * 256 + lane * 4;
            float p = le[0] * wa[0] + le[1] * wa[1] + le[2] * wa[2] + le[3] * wa[3];
            #pragma unroll
            for (int off = 32; off > 0; off >>= 1) p += __shfl_xor(p, off, 64);
            if (lane == 0) ldot[l * 8 + pair] = p;
        }
    }
    __syncthreads();
    int c = t & 255, half = t >> 8;
    float bv = bf_s[c];
    float* xb = xtok + (size_t)b * 196 * 256 + c;
    for (int r = half; r < 196; r += 2) xb[(size_t)r * 256] = bv;
}

// -------- K3: lateral projection, 8 K-slices, atomic epilogue (round-2-proven) --------
__global__ __launch_bounds__(256) void lateral_slice(
    const float* __restrict__ pf0, const float* __restrict__ pf1,
    const float* __restrict__ pf2, const float* __restrict__ pf3,
    const float* __restrict__ w0, const float* __restrict__ w1,
    const float* __restrict__ w2, const float* __restrict__ w3,
    const float* __restrict__ sw, float* __restrict__ xtok)
{
    const int sArr[8]    = {0, 1, 2, 2, 3, 3, 3, 3};
    const int koffArr[8] = {0, 0, 0, 512, 0, 512, 1024, 1536};
    const int klenArr[8] = {256, 512, 512, 512, 512, 512, 512, 512};
    int sl = blockIdx.y;
    int s = sArr[sl], koff = koffArr[sl], klen = klenArr[sl];
    const float* pf = (s == 0) ? pf0 : (s == 1) ? pf1 : (s == 2) ? pf2 : pf3;
    const float* W  = (s == 0) ? w0  : (s == 1) ? w1  : (s == 2) ? w2  : w3;

    int mt = blockIdx.x % 49, nt = blockIdx.x / 49;
    int m0 = mt * 32, n0 = nt * 64;
    __shared__ alignas(16) unsigned short As[1024];
    __shared__ alignas(16) unsigned short Bs[2048];
    int t = threadIdx.x, lane = t & 63, wid = t >> 6;
    int wm = wid >> 1, wn = wid & 1;
    f32x4 acc0 = {0, 0, 0, 0}, acc1 = {0, 0, 0, 0};

    int f = t & 63;
    int mA = m0 + ((t >> 6) & 1) * 16 + (f & 15);   // t<128
    int kbA = (f >> 4) * 8;
    int nB = n0 + (t >> 6) * 16 + (f & 15);
    int kbB = (f >> 4) * 8;
    float swv = sw[(mA / 196) * 4 + s];

    float ar[8], br[8];
    auto loadA = [&](int k0) {
        if (t < 128) {
            const float* base = pf + (size_t)(koff + k0 + kbA) * 1568 + mA;
            #pragma unroll
            for (int j = 0; j < 8; j++) ar[j] = base[(size_t)j * 1568] * swv;
        }
    };
    auto loadB = [&](int k0) {
        const float* base = W + (size_t)(koff + k0 + kbB) * 256 + nB;
        #pragma unroll
        for (int j = 0; j < 8; j++) br[j] = base[(size_t)j * 256];
    };

    loadA(0); loadB(0);
    for (int k0 = 0; k0 < klen; k0 += 32) {
        if (t < 128) *(bshort8*)&As[(((t >> 6) & 1) * 512 + f * 8)] = pack8(ar);
        *(bshort8*)&Bs[((t >> 6) * 512 + f * 8)] = pack8(br);
        __syncthreads();
        if (k0 + 32 < klen) { loadA(k0 + 32); loadB(k0 + 32); }
        bshort8 av = *(const bshort8*)&As[wm * 512 + lane * 8];
        bshort8 bv0 = *(const bshort8*)&Bs[(wn * 2 + 0) * 512 + lane * 8];
        bshort8 bv1 = *(const bshort8*)&Bs[(wn * 2 + 1) * 512 + lane * 8];
        acc0 = mfma16(av, bv0, acc0);
        acc1 = mfma16(av, bv1, acc1);
        __syncthreads();
    }
    int col0 = n0 + wn * 32 + (lane & 15);
    int rbase = m0 + wm * 16 + ((lane >> 4) << 2);
    #pragma unroll
    for (int r = 0; r < 4; r++) {
        int m = rbase + r;
        atomicAdd(&xtok[(size_t)m * 256 + col0], acc0[r]);
        atomicAdd(&xtok[(size_t)m * 256 + col0 + 16], acc1[r]);
    }
}

// -------- generic bf16-MFMA GEMM --------
template <bool B_IS_KXN>
__global__ __launch_bounds__(256) void gemm_kernel(
    const float* __restrict__ Ab, int lda, long long sAy, long long sAz,
    const float* __restrict__ Bb, int ldb, long long sBy, long long sBz,
    float* __restrict__ Cb, int ldc, long long sCy, long long sCz,
    const float* __restrict__ bias, int M, int N, int K,
    float alpha, int mtiles)
{
    const float* A = Ab + blockIdx.y * sAy + blockIdx.z * sAz;
    const float* B = Bb + blockIdx.y * sBy + blockIdx.z * sBz;
    float* C = Cb + blockIdx.y * sCy + blockIdx.z * sCz;
    int mt = blockIdx.x % mtiles, nt = blockIdx.x / mtiles;
    int m0 = mt * 32, n0 = nt * 64;
    __shared__ alignas(16) unsigned short As[1024];
    __shared__ alignas(16) unsigned short Bs[2048];
    int t = threadIdx.x, lane = t & 63, wid = t >> 6;
    int wm = wid >> 1, wn = wid & 1;
    f32x4 acc0 = {0, 0, 0, 0}, acc1 = {0, 0, 0, 0};

    int f = t & 63;
    int mA = m0 + ((t >> 6) & 1) * 16 + (f & 15);   // t<128
    int kbA = (f >> 4) * 8;
    int nB = n0 + (t >> 6) * 16 + (f & 15);
    int kbB = (f >> 4) * 8;

    float ar[8], br[8];
    auto loadA = [&](int k0) {
        if (t < 128) {
            int kb = k0 + kbA;
            if (mA < M && kb + 8 <= K) {
                const float4* p = (const float4*)(A + (size_t)mA * lda + kb);
                float4 u = p[0], v = p[1];
                ar[0] = u.x; ar[1] = u.y; ar[2] = u.z; ar[3] = u.w;
                ar[4] = v.x; ar[5] = v.y; ar[6] = v.z; ar[7] = v.w;
            } else {
                #pragma unroll
                for (int j = 0; j < 8; j++) {
                    int k = kb + j;
                    ar[j] = (mA < M && k < K) ? A[(size_t)mA * lda + k] : 0.f;
                }
            }
        }
    };
    auto loadB = [&](int k0) {
        int kb = k0 + kbB;
        if constexpr (B_IS_KXN) {
            #pragma unroll
            for (int j = 0; j < 8; j++) {
                int k = kb + j;
                br[j] = (k < K && nB < N) ? B[(size_t)k * ldb + nB] : 0.f;
            }
        } else {
            if (nB < N && kb + 8 <= K) {
                const float4* p = (const float4*)(B + (size_t)nB * ldb + kb);
                float4 u = p[0], v = p[1];
                br[0] = u.x; br[1] = u.y; br[2] = u.z; br[3] = u.w;
                br[4] = v.x; br[5] = v.y; br[6] = v.z; br[7] = v.w;
            } else {
                #pragma unroll
                for (int j = 0; j < 8; j++) {
                    int k = kb + j;
                    br[j] = (nB < N && k < K) ? B[(size_t)nB * ldb + k] : 0.f;
                }
            }
        }
    };

    loadA(0); loadB(0);
    for (int k0 = 0; k0 < K; k0 += 32) {
        if (t < 128) *(bshort8*)&As[(((t >> 6) & 1) * 512 + f * 8)] = pack8(ar);
        *(bshort8*)&Bs[((t >> 6) * 512 + f * 8)] = pack8(br);
        __syncthreads();
        if (k0 + 32 < K) { loadA(k0 + 32); loadB(k0 + 32); }
        bshort8 av = *(const bshort8*)&As[wm * 512 + lane * 8];
        bshort8 bv0 = *(const bshort8*)&Bs[(wn * 2 + 0) * 512 + lane * 8];
        bshort8 bv1 = *(const bshort8*)&Bs[(wn * 2 + 1) * 512 + lane * 8];
        acc0 = mfma16(av, bv0, acc0);
        acc1 = mfma16(av, bv1, acc1);
        __syncthreads();
    }
    int col0 = n0 + wn * 32 + (lane & 15);
    int rbase = m0 + wm * 16 + ((lane >> 4) << 2);
    #pragma unroll
    for (int r = 0; r < 4; r++) {
        int m = rbase + r;
        if (m < M) {
            if (col0 < N) {
                float v = acc0[r] * alpha;
                if (bias) v += bias[col0];
                C[(size_t)m * ldc + col0] = v;
            }
            int c1 = col0 + 16;
            if (c1 < N) {
                float v = acc1[r] * alpha;
                if (bias) v += bias[c1];
                C[(size_t)m * ldc + c1] = v;
            }
        }
    }
}

// -------- attention softmax over rows of S [12544][196], in place --------
__global__ __launch_bounds__(256) void attn_softmax(float* __restrict__ S)
{
    int wid = threadIdx.x >> 6, lane = threadIdx.x & 63;
    size_t row = (size_t)blockIdx.x * 4 + wid;
    float* p = S + row * 196;
    float v0 = p[lane];
    float v1 = p[64 + lane];
    float v2 = p[128 + lane];
    float v3 = (lane < 4) ? p[192 + lane] : -1e30f;
    float mx = fmaxf(fmaxf(v0, v1), fmaxf(v2, v3));
    #pragma unroll
    for (int off = 32; off > 0; off >>= 1) mx = fmaxf(mx, __shfl_xor(mx, off, 64));
    float e0 = expf(v0 - mx), e1 = expf(v1 - mx), e2 = expf(v2 - mx);
    float e3 = (lane < 4) ? expf(v3 - mx) : 0.f;
    float sum = e0 + e1 + e2 + e3;
    #pragma unroll
    for (int off = 32; off > 0; off >>= 1) sum += __shfl_xor(sum, off, 64);
    float inv = 1.f / sum;
    p[lane] = e0 * inv;
    p[64 + lane] = e1 * inv;
    p[128 + lane] = e2 * inv;
    if (lane < 4) p[192 + lane] = e3 * inv;
}

// ================= tail, stage 1: one block per (b,h) — 32 blocks =================
// xm/gctx computed redundantly per head (reads are L2/L3-cached). Produces atts
// (output 6) and hm[b][h][256] in workspace. Algebra: Σ_j att_row[j] = 1 per row so
// col-sum am_raw has Σ_l am_raw[l] = 80; av = (am_raw·lemb)/80 + gctx.
__global__ __launch_bounds__(1024) void tail1(
    const float* __restrict__ xo, const float* __restrict__ proj_w,
    const float* __restrict__ proj_b,
    const float* __restrict__ gat_W, const float* __restrict__ lemb,
    const float* __restrict__ Wa, const float* __restrict__ ldot,
    float* __restrict__ atts, float* __restrict__ hm_g)
{
    int b = blockIdx.x >> 2, h = blockIdx.x & 3;
    int t = threadIdx.x, lane = t & 63, wv = t >> 6;
    __shared__ float red[1024];
    __shared__ float xm[256];
    __shared__ float gctx_s[256];
    __shared__ float gdot_s[2];
    __shared__ float s12h[160];
    __shared__ float am_s[80];
    __shared__ float av_s[256];

    // ---- P0: xm = token-mean of xo[b] ----
    {
        int c = t & 255, sl = t >> 8;
        const float* base = xo + ((size_t)b * 196 + sl * 49) * 256 + c;
        float s = 0.f;
        #pragma unroll 7
        for (int i = 0; i < 49; i++) s += base[(size_t)i * 256];
        red[t] = s;
    }
    if (t < 80) am_s[t] = 0.f;
    __syncthreads();
    if (t < 256) xm[t] = (red[t] + red[256 + t] + red[512 + t] + red[768 + t]) * (1.f / 196.f);
    __syncthreads();

    // ---- P1: gctx = xm @ proj_w + proj_b ----
    {
        int n = t & 255, ks = t >> 8;
        float acc = 0.f;
        const float* w = proj_w + (size_t)(ks * 64) * 256 + n;
        #pragma unroll 8
        for (int i = 0; i < 64; i++) acc += xm[ks * 64 + i] * w[(size_t)i * 256];
        red[t] = acc;
    }
    __syncthreads();
    if (t < 256) gctx_s[t] = proj_b[t] + red[t] + red[256 + t] + red[512 + t] + red[768 + t];
    __syncthreads();

    // ---- P2: gdot for this head's two pairs; s12h = ldot + gdot ----
    if (wv < 2) {
        int pair = h * 2 + wv;
        const float* wa = Wa + pair * 256 + lane * 4;
        float p = gctx_s[lane * 4] * wa[0] + gctx_s[lane * 4 + 1] * wa[1]
                + gctx_s[lane * 4 + 2] * wa[2] + gctx_s[lane * 4 + 3] * wa[3];
        #pragma unroll
        for (int off = 32; off > 0; off >>= 1) p += __shfl_xor(p, off, 64);
        if (lane == 0) gdot_s[wv] = p;
    }
    __syncthreads();
    if (t < 160) {
        int q = t / 80, l = t - q * 80;
        s12h[t] = ldot[l * 8 + h * 2 + q] + gdot_s[q];
    }
    __syncthreads();

    // ---- P3: GAT row softmax (80 rows over 16 waves) -> atts + am accumulation ----
    {
        #pragma unroll
        for (int rr = 0; rr < 5; rr++) {
            int i = rr * 16 + wv;
            float s1i = s12h[i];
            const float* s2 = s12h + 80;
            float v0 = s1i + s2[lane]; v0 = v0 > 0.f ? v0 : 0.2f * v0;
            float v1 = -1e30f;
            if (lane < 16) { v1 = s1i + s2[64 + lane]; v1 = v1 > 0.f ? v1 : 0.2f * v1; }
            float mx = fmaxf(v0, v1);
            #pragma unroll
            for (int off = 32; off > 0; off >>= 1) mx = fmaxf(mx, __shfl_xor(mx, off, 64));
            float e0 = expf(v0 - mx), e1 = (lane < 16) ? expf(v1 - mx) : 0.f;
            float sum = e0 + e1;
            #pragma unroll
            for (int off = 32; off > 0; off >>= 1) sum += __shfl_xor(sum, off, 64);
            float inv = 1.f / sum;
            float* orow = atts + (size_t)h * 51200 + b * 6400 + i * 80;
            float p0 = e0 * inv;
            orow[lane] = p0;
            atomicAdd(&am_s[lane], p0);
            if (lane < 16) {
                float p1 = e1 * inv;
                orow[64 + lane] = p1;
                atomicAdd(&am_s[64 + lane], p1);
            }
        }
    }
    __syncthreads();

    // ---- P4: av = (am_raw . lemb)/80 + gctx; hm = av @ gat_W[h] ----
    {
        int n = t & 255, ks = t >> 8;
        float acc = 0.f;
        const float* le = lemb + n;
        #pragma unroll 5
        for (int l = ks * 20; l < ks * 20 + 20; l++) acc += am_s[l] * le[(size_t)l * 256];
        red[t] = acc;
    }
    __syncthreads();
    if (t < 256)
        av_s[t] = (red[t] + red[256 + t] + red[512 + t] + red[768 + t]) * (1.f / 80.f)
                + gctx_s[t];
    __syncthreads();
    {
        int n = t & 255, ks = t >> 8;
        float acc = 0.f;
        const float* w = gat_W + (size_t)h * 65536 + (size_t)(ks * 64) * 256 + n;
        #pragma unroll 8
        for (int i = 0; i < 64; i++) acc += av_s[ks * 64 + i] * w[(size_t)i * 256];
        red[t] = acc;
    }
    __syncthreads();
    if (t < 256)
        hm_g[(b * 4 + h) * 256 + t] = red[t] + red[256 + t] + red[512 + t] + red[768 + t];
}

// ================= tail, stage 2: one block per b — 8 blocks =================
__global__ __launch_bounds__(1024) void tail2(
    const float* __restrict__ hm_g,
    const float* __restrict__ out_w, const float* __restrict__ out_b,
    const float* __restrict__ spec_w1, const float* __restrict__ spec_b1,
    const float* __restrict__ spec_w2, const float* __restrict__ spec_b2,
    const float* __restrict__ spat_w1, const float* __restrict__ spat_b1,
    const float* __restrict__ spat_w2, const float* __restrict__ spat_b2,
    const float* __restrict__ gate_w, const float* __restrict__ gate_b,
    const float* __restrict__ unc_w, const float* __restrict__ unc_b,
    float* __restrict__ out)
{
    int b = blockIdx.x, t = threadIdx.x;
    __shared__ float red[1024];
    __shared__ float as_s[256];
    __shared__ float hb_s[256];
    __shared__ float fv_s[320];

    // ---- P5: a_s = concat(hm) @ out_w + out_b ----
    {
        int n = t & 255, ks = t >> 8;
        float acc = 0.f;
        const float* hv = hm_g + b * 1024 + ks * 256;
        const float* w = out_w + (size_t)(ks * 256) * 256 + n;
        #pragma unroll 8
        for (int k = 0; k < 256; k++) acc += hv[k] * w[(size_t)k * 256];
        red[t] = acc;
    }
    __syncthreads();
    if (t < 256) as_s[t] = out_b[t] + red[t] + red[256 + t] + red[512 + t] + red[768 + t];
    __syncthreads();

    // ---- P6: hidden = relu(a_s @ w1 + b1) for spec (u<128) and spat (u>=128) ----
    {
        int u = t & 255, ks = t >> 8;
        int which = u >> 7, oo = u & 127;
        const float* w1 = which ? spat_w1 : spec_w1;
        float acc = 0.f;
        #pragma unroll 8
        for (int i = 0; i < 64; i++) {
            int k = ks * 64 + i;
            acc += as_s[k] * w1[(size_t)k * 128 + oo];
        }
        red[t] = acc;
    }
    __syncthreads();
    if (t < 256) {
        int which = t >> 7, oo = t & 127;
        const float* b1 = which ? spat_b1 : spec_b1;
        hb_s[t] = fmaxf(red[t] + red[256 + t] + red[512 + t] + red[768 + t] + b1[oo], 0.f);
    }
    __syncthreads();

    // ---- P7: head pre-activations fv[head][80], 3-way split-K ----
    if (t < 960) {
        int sub = t / 320, u = t - sub * 320;
        int head = u / 80, o = u - head * 80;
        const float* wp; const float* src; int K;
        if (head == 0)      { wp = spec_w2; src = hb_s;       K = 128; }
        else if (head == 1) { wp = spat_w2; src = hb_s + 128; K = 128; }
        else if (head == 2) { wp = gate_w;  src = as_s;       K = 256; }
        else                { wp = unc_w;   src = as_s;       K = 256; }
        int k0 = (K * sub) / 3, k1 = (K * (sub + 1)) / 3;
        float acc = 0.f;
        for (int k = k0; k < k1; k++) acc += src[k] * wp[(size_t)k * 80 + o];
        red[sub * 320 + u] = acc;
    }
    __syncthreads();
    if (t < 320) {
        int head = t / 80, o = t - head * 80;
        const float* bp = head == 0 ? spec_b2 : head == 1 ? spat_b2 : head == 2 ? gate_b : unc_b;
        fv_s[t] = red[t] + red[320 + t] + red[640 + t] + bp[o];
    }
    __syncthreads();

    // ---- P8: final combine ----
    if (t < 80) {
        float sp = fv_s[t], st2 = fv_s[80 + t], gz = fv_s[160 + t], uz = fv_s[240 + t];
        float g = 1.f / (1.f + expf(-gz));
        out[b * 80 + t] = g * sp + (1.f - g) * st2;
        out[640 + b * 80 + t] = sp;
        out[1280 + b * 80 + t] = st2;
        out[1920 + b * 80 + t] = g;
        red[t] = log1pf(expf(uz)) + 1.f;
    }
    __syncthreads();
    if (t == 0) {
        float s = 0.f;
        for (int l = 0; l < 80; l++) s += red[l];
        out[2560 + b] = 80.f / s;
    }
}

// ---------------- launcher ----------------
extern "C" void kernel_launch(void* const* d_in, const int* in_sizes, int n_in,
                              void* d_out, int out_size, void* d_ws, size_t ws_size,
                              hipStream_t stream)
{
    (void)in_sizes; (void)n_in; (void)out_size; (void)ws_size;
    const float* c2 = (const float*)d_in[0];
    const float* c3 = (const float*)d_in[1];
    const float* c4 = (const float*)d_in[2];
    const float* c5 = (const float*)d_in[3];
    const float* lat_w0 = (const float*)d_in[4];
    const float* lat_b0 = (const float*)d_in[5];
    const float* lat_w1 = (const float*)d_in[6];
    const float* lat_b1 = (const float*)d_in[7];
    const float* lat_w2 = (const float*)d_in[8];
    const float* lat_b2 = (const float*)d_in[9];
    const float* lat_w3 = (const float*)d_in[10];
    const float* lat_b3 = (const float*)d_in[11];
    const float* sp_w1 = (const float*)d_in[12];
    const float* sp_b1 = (const float*)d_in[13];
    const float* sp_w2 = (const float*)d_in[14];
    const float* sp_b2 = (const float*)d_in[15];
    const float* qkv_w = (const float*)d_in[16];
    const float* qkv_b = (const float*)d_in[17];
    const float* proj_w = (const float*)d_in[18];
    const float* proj_b = (const float*)d_in[19];
    const float* gat_W = (const float*)d_in[20];
    const float* gat_a = (const float*)d_in[21];
    const float* out_w = (const float*)d_in[22];
    const float* out_b = (const float*)d_in[23];
    const float* label_emb = (const float*)d_in[24];
    const float* spec_w1 = (const float*)d_in[25];
    const float* spec_b1 = (const float*)d_in[26];
    const float* spec_w2 = (const float*)d_in[27];
    const float* spec_b2 = (const float*)d_in[28];
    const float* spat_w1 = (const float*)d_in[29];
    const float* spat_b1 = (const float*)d_in[30];
    const float* spat_w2 = (const float*)d_in[31];
    const float* spat_b2 = (const float*)d_in[32];
    const float* gate_w = (const float*)d_in[33];
    const float* gate_b = (const float*)d_in[34];
    const float* unc_w = (const float*)d_in[35];
    const float* unc_b = (const float*)d_in[36];

    float* out = (float*)d_out;
    float* ws = (float*)d_ws;

    // workspace layout (floats); later phases reuse dead regions
    float* pf0    = ws + 0;        // 401408
    float* pf1    = ws + 401408;
    float* pf2    = ws + 1204224;
    float* pf3    = ws + 2809856;  // ends 6021120
    float* pooled = ws + 6021120;  // 16384  -> 6037504
    float* swpart = ws + 6039552;  // 32768  -> 6072320
    float* Wa     = ws + 6072320;  // 2048   -> 6074368
    float* ldot   = ws + 6074368;  // 640    -> 6075008
    float* qkv    = ws + 0;        // reuses pf0/pf1 (dead after lateral)
    float* S      = ws + 1204224;  // reuses pf2/pf3 (dead after lateral)
    float* xo     = ws + 3662848;  // 401408 -> 4064256
    float* hm_g   = ws + 4253696;  // 8192   -> 4261888
    float* xtok   = ws + 6106112;  // 401408 -> 6507520

    float* swp  = out + 2568;  // sw [8,4] (output 5)
    float* atts = out + 2600;  // atts [4,8,80,80] (output 6)

    // 1. ALL pools + c5 mean in one dispatch
    pool_all<<<27616, 256, 0, stream>>>(c2, c3, c4, c5, pf0, pf1, pf2, pf3, pooled);
    // 2. scale-weight MLP partials + hoisted Wa (16 extra blocks)
    sw_part<<<dim3(8, 10), 512, 0, stream>>>(pooled, sp_w1, swpart, gat_W, gat_a, Wa);
    // 2b. finish sw MLP + bias-init xtok + hoisted ldot
    sw_fin<<<8, 512, 0, stream>>>(swpart, sp_b1, sp_w2, sp_b2,
                                  lat_b0, lat_b1, lat_b2, lat_b3,
                                  label_emb, Wa, swp, xtok, ldot);
    // 3. lateral projection + sw combine -> x tokens [1568,256] (8 K-slices, atomic)
    lateral_slice<<<dim3(196, 8), 256, 0, stream>>>(pf0, pf1, pf2, pf3,
                                                    lat_w0, lat_w1, lat_w2, lat_w3,
                                                    swp, xtok);
    // 4. qkv = x @ qkv_w + qkv_b : [1568,768]
    gemm_kernel<true><<<dim3(49 * 12, 1, 1), 256, 0, stream>>>(
        xtok, 256, 0, 0, qkv_w, 768, 0, 0, qkv, 768, 0, 0,
        qkv_b, 1568, 768, 256, 1.f, 49);
    // 5. S = q @ k^T * hd^-0.5, per (b,h) : [64,196,196]
    gemm_kernel<false><<<dim3(7 * 4, 8, 8), 256, 0, stream>>>(
        qkv, 768, 150528, 32, qkv + 256, 768, 150528, 32,
        S, 196, 307328, 38416, nullptr, 196, 196, 32, 0.17677669529663687f, 7);
    // 6. row softmax on S (in place)
    attn_softmax<<<3136, 256, 0, stream>>>(S);
    // 7. xo = P @ v : [1568,256] (head-concat layout)
    gemm_kernel<true><<<dim3(7, 8, 8), 256, 0, stream>>>(
        S, 196, 307328, 38416, qkv + 512, 768, 150528, 32,
        xo, 256, 50176, 32, nullptr, 196, 32, 196, 1.f, 7);
    // 8. tail stage 1: per (b,h) — gctx/s12/softmax/av/hm (32 blocks)
    tail1<<<32, 1024, 0, stream>>>(xo, proj_w, proj_b, gat_W, label_emb,
                                   Wa, ldot, atts, hm_g);
    // 9. tail stage 2: per b — a_s/MLPs/heads/combine (8 blocks)
    tail2<<<8, 1024, 0, stream>>>(hm_g, out_w, out_b,
                                  spec_w1, spec_b1, spec_w2, spec_b2,
                                  spat_w1, spat_b1, spat_w2, spat_b2,
                                  gate_w, gate_b, unc_w, unc_b, out);
}

// Round 6
// 494.096 us; speedup vs baseline: 1.3374x; 1.0266x over previous
//
#include <hip/hip_runtime.h>
#include <math.h>

typedef __attribute__((ext_vector_type(8))) short bshort8;
typedef __attribute__((ext_vector_type(4))) float f32x4;

#define DI __device__ __forceinline__

DI unsigned short f2bf(float x) {
    unsigned int u = __builtin_bit_cast(unsigned int, x);
    u += 0x7fffu + ((u >> 16) & 1u);
    return (unsigned short)(u >> 16);
}

DI bshort8 pack8(const float* v) {
    bshort8 r;
    #pragma unroll
    for (int j = 0; j < 8; j++) r[j] = (short)f2bf(v[j]);
    return r;
}

DI f32x4 mfma16(bshort8 a, bshort8 b, f32x4 c) {
    return __builtin_amdgcn_mfma_f32_16x16x32_bf16(a, b, c, 0, 0, 0);
}

// ---- composite (bilinear resize N->112, align_corners=False) + 8x8 avgpool stencils ----
__device__ const float W14[14][3] = {
    {0.875f, 0.125f, 0.f},
    {0.125f, 0.75f, 0.125f}, {0.125f, 0.75f, 0.125f}, {0.125f, 0.75f, 0.125f},
    {0.125f, 0.75f, 0.125f}, {0.125f, 0.75f, 0.125f}, {0.125f, 0.75f, 0.125f},
    {0.125f, 0.75f, 0.125f}, {0.125f, 0.75f, 0.125f}, {0.125f, 0.75f, 0.125f},
    {0.125f, 0.75f, 0.125f}, {0.125f, 0.75f, 0.125f}, {0.125f, 0.75f, 0.125f},
    {0.125f, 0.875f, 0.f}};
__device__ const float W28[14][4] = {
    {0.5f, 0.4375f, 0.0625f, 0.f},
    {0.0625f, 0.4375f, 0.4375f, 0.0625f}, {0.0625f, 0.4375f, 0.4375f, 0.0625f},
    {0.0625f, 0.4375f, 0.4375f, 0.0625f}, {0.0625f, 0.4375f, 0.4375f, 0.0625f},
    {0.0625f, 0.4375f, 0.4375f, 0.0625f}, {0.0625f, 0.4375f, 0.4375f, 0.0625f},
    {0.0625f, 0.4375f, 0.4375f, 0.0625f}, {0.0625f, 0.4375f, 0.4375f, 0.0625f},
    {0.0625f, 0.4375f, 0.4375f, 0.0625f}, {0.0625f, 0.4375f, 0.4375f, 0.0625f},
    {0.0625f, 0.4375f, 0.4375f, 0.0625f}, {0.0625f, 0.4375f, 0.4375f, 0.0625f},
    {0.0625f, 0.4375f, 0.5f, 0.f}};
__device__ const float W56[14][6] = {
    {0.25f, 0.25f, 0.25f, 0.21875f, 0.03125f, 0.f},
    {0.03125f, 0.21875f, 0.25f, 0.25f, 0.21875f, 0.03125f},
    {0.03125f, 0.21875f, 0.25f, 0.25f, 0.21875f, 0.03125f},
    {0.03125f, 0.21875f, 0.25f, 0.25f, 0.21875f, 0.03125f},
    {0.03125f, 0.21875f, 0.25f, 0.25f, 0.21875f, 0.03125f},
    {0.03125f, 0.21875f, 0.25f, 0.25f, 0.21875f, 0.03125f},
    {0.03125f, 0.21875f, 0.25f, 0.25f, 0.21875f, 0.03125f},
    {0.03125f, 0.21875f, 0.25f, 0.25f, 0.21875f, 0.03125f},
    {0.03125f, 0.21875f, 0.25f, 0.25f, 0.21875f, 0.03125f},
    {0.03125f, 0.21875f, 0.25f, 0.25f, 0.21875f, 0.03125f},
    {0.03125f, 0.21875f, 0.25f, 0.25f, 0.21875f, 0.03125f},
    {0.03125f, 0.21875f, 0.25f, 0.25f, 0.21875f, 0.03125f},
    {0.03125f, 0.21875f, 0.25f, 0.25f, 0.21875f, 0.03125f},
    {0.03125f, 0.21875f, 0.25f, 0.25f, 0.25f, 0.f}};

// -------- pooled-feature bodies; pf layout [cin][1568] bf16, col = b*196 + r --------
// Explicit register batching: issue ALL loads before reducing (MLP; VGPR up on purpose).
template <int N, int C, int TAPS>
DI void pool_body(const float* __restrict__ src, unsigned short* __restrict__ dst,
                  unsigned blk, unsigned t)
{
    unsigned id = blk * 256u + t;
    unsigned p = id / 196u;
    unsigned r = id - p * 196u;
    unsigned ti = r / 14u, tj = r - ti * 14u;
    unsigned b = p / C, cin = p - b * C;
    const float* plane = src + (size_t)p * (N * N);
    float acc = 0.f;
    if constexpr (N == 112) {
        const float4* p4 = (const float4*)(plane + (size_t)(ti * 8) * 112 + tj * 8);
        float4 rv[16];
        #pragma unroll
        for (int i = 0; i < 8; i++) { rv[2 * i] = p4[i * 28]; rv[2 * i + 1] = p4[i * 28 + 1]; }
        #pragma unroll
        for (int i = 0; i < 16; i++) acc += (rv[i].x + rv[i].y) + (rv[i].z + rv[i].w);
        acc *= (1.f / 64.f);
    } else {
        constexpr int STRIDE = N / 14;
        const float (*WT)[TAPS] = (N == 14) ? (const float (*)[TAPS])W14
                                : (N == 28) ? (const float (*)[TAPS])W28
                                            : (const float (*)[TAPS])W56;
        int hs = (int)(STRIDE * ti) - 1; if (hs < 0) hs = 0;
        int ws = (int)(STRIDE * tj) - 1; if (ws < 0) ws = 0;
        float wh[TAPS], ww[TAPS];
        #pragma unroll
        for (int i = 0; i < TAPS; i++) { wh[i] = WT[ti][i]; ww[i] = WT[tj][i]; }
        float rv[TAPS][TAPS];
        #pragma unroll
        for (int i = 0; i < TAPS; i++) {
            int hi = hs + i; if (hi > N - 1) hi = N - 1;
            const float* row = plane + (size_t)hi * N;
            #pragma unroll
            for (int j = 0; j < TAPS; j++) {
                int wj = ws + j; if (wj > N - 1) wj = N - 1;
                rv[i][j] = row[wj];
            }
        }
        #pragma unroll
        for (int i = 0; i < TAPS; i++) {
            float rs = 0.f;
            #pragma unroll
            for (int j = 0; j < TAPS; j++) rs += ww[j] * rv[i][j];
            acc += wh[i] * rs;
        }
    }
    dst[(size_t)cin * 1568 + b * 196 + r] = f2bf(acc);
}

DI void c5_mean_body(const float* __restrict__ c5, float* __restrict__ pooled,
                     unsigned blk, unsigned t)
{
    int wid = t >> 6, lane = t & 63;
    int p = blk * 4 + wid;
    const float* plane = c5 + (size_t)p * 196;
    float v = plane[lane] + plane[64 + lane] + plane[128 + lane];
    if (lane < 4) v += plane[192 + lane];
    #pragma unroll
    for (int off = 32; off > 0; off >>= 1) v += __shfl_xor(v, off, 64);
    if (lane == 0) pooled[p] = v * (1.f / 196.f);
}

// -------- K1: all four scale pools + c5 mean in ONE dispatch --------
__global__ __launch_bounds__(256) void pool_all(
    const float* __restrict__ c2, const float* __restrict__ c3,
    const float* __restrict__ c4, const float* __restrict__ c5,
    unsigned short* __restrict__ pf0, unsigned short* __restrict__ pf1,
    unsigned short* __restrict__ pf2, unsigned short* __restrict__ pf3,
    float* __restrict__ pooled)
{
    unsigned bx = blockIdx.x, t = threadIdx.x;
    if (bx < 1568u)       pool_body<112, 256, 8>(c2, pf0, bx, t);
    else if (bx < 4704u)  pool_body<56, 512, 6>(c3, pf1, bx - 1568u, t);
    else if (bx < 10976u) pool_body<28, 1024, 4>(c4, pf2, bx - 4704u, t);
    else if (bx < 23520u) pool_body<14, 2048, 3>(c5, pf3, bx - 10976u, t);
    else                  c5_mean_body(c5, pooled, bx - 23520u, t);
}

// -------- K2a: partial GEMV for sw MLP layer 1 (split-K) + hoisted Wa (y>=8) --------
__global__ __launch_bounds__(512) void sw_part(
    const float* __restrict__ pooled, const float* __restrict__ sp_w1,
    float* __restrict__ partial,
    const float* __restrict__ gat_W, const float* __restrict__ gat_a,
    float* __restrict__ Wa)
{
    int t = threadIdx.x;
    if (blockIdx.y >= 8) {
        int e = (blockIdx.y - 8) * 8 + blockIdx.x;   // [0,16)
        int h = e >> 2, q = e & 3;
        __shared__ float a1[256], a2[256];
        if (t < 256) { a1[t] = gat_a[h * 512 + t]; a2[t] = gat_a[h * 512 + 256 + t]; }
        __syncthreads();
        int w = t >> 6, lane = t & 63;
        #pragma unroll
        for (int ci = 0; ci < 8; ci++) {
            int c = q * 64 + w * 8 + ci;
            const float* row = gat_W + (size_t)h * 65536 + (size_t)c * 256;
            float p1 = 0.f, p2 = 0.f;
            #pragma unroll
            for (int jj = 0; jj < 4; jj++) {
                float v = row[lane + 64 * jj];
                p1 += v * a1[lane + 64 * jj];
                p2 += v * a2[lane + 64 * jj];
            }
            #pragma unroll
            for (int off = 32; off > 0; off >>= 1) {
                p1 += __shfl_xor(p1, off, 64);
                p2 += __shfl_xor(p2, off, 64);
            }
            if (lane == 0) { Wa[h * 512 + c] = p1; Wa[h * 512 + 256 + c] = p2; }
        }
        return;
    }
    int b = blockIdx.x, kc = blockIdx.y;
    __shared__ float ps[256];
    if (t < 256) ps[t] = pooled[b * 2048 + kc * 256 + t];
    __syncthreads();
    float acc = 0.f;
    const float* w = sp_w1 + (size_t)(kc * 256) * 512 + t;
    #pragma unroll 8
    for (int c = 0; c < 256; c++) acc += ps[c] * w[(size_t)c * 512];
    partial[((size_t)b * 8 + kc) * 512 + t] = acc;
}

// -------- K2b: finish sw MLP + bias-init xtok + hoisted ldot = lemb @ Wa^T --------
__global__ __launch_bounds__(512) void sw_fin(
    const float* __restrict__ partial, const float* __restrict__ sp_b1,
    const float* __restrict__ sp_w2, const float* __restrict__ sp_b2,
    const float* __restrict__ lb0, const float* __restrict__ lb1,
    const float* __restrict__ lb2, const float* __restrict__ lb3,
    const float* __restrict__ lemb, const float* __restrict__ Wa,
    float* __restrict__ sw_out, float* __restrict__ xtok,
    float* __restrict__ ldot)
{
    int b = blockIdx.x, t = threadIdx.x;
    __shared__ float h[512];
    __shared__ float s4s[4];
    __shared__ float swl[4];
    __shared__ float bf_s[256];
    float a = sp_b1[t];
    #pragma unroll
    for (int kc = 0; kc < 8; kc++) a += partial[((size_t)b * 8 + kc) * 512 + t];
    h[t] = fmaxf(a, 0.f);
    __syncthreads();
    int wv = t >> 6, lane = t & 63;
    if (wv < 4) {
        float acc = 0.f;
        #pragma unroll
        for (int i = 0; i < 8; i++) {
            int idx = lane + 64 * i;
            acc += h[idx] * sp_w2[idx * 4 + wv];
        }
        #pragma unroll
        for (int off = 32; off > 0; off >>= 1) acc += __shfl_xor(acc, off, 64);
        if (lane == 0) s4s[wv] = acc + sp_b2[wv];
    }
    __syncthreads();
    if (t == 0) {
        float mx = fmaxf(fmaxf(s4s[0], s4s[1]), fmaxf(s4s[2], s4s[3]));
        float e0 = expf(s4s[0] - mx), e1 = expf(s4s[1] - mx);
        float e2 = expf(s4s[2] - mx), e3 = expf(s4s[3] - mx);
        float inv = 1.f / (e0 + e1 + e2 + e3);
        swl[0] = e0 * inv; swl[1] = e1 * inv; swl[2] = e2 * inv; swl[3] = e3 * inv;
        for (int o = 0; o < 4; o++) sw_out[b * 4 + o] = swl[o];
    }
    __syncthreads();
    if (t < 256)
        bf_s[t] = swl[0] * lb0[t] + swl[1] * lb1[t] + swl[2] * lb2[t] + swl[3] * lb3[t];
    // hoisted: ldot[l][pair] = dot(lemb[l], Wa[pair]); block b handles l = 10b..10b+9
    {
        int pair = t >> 6;
        #pragma unroll
        for (int r = 0; r < 10; r++) {
            int l = b * 10 + r;
            const float* le = lemb + l * 256 + lane * 4;
            const float* wa = Wa + pair * 256 + lane * 4;
            float p = le[0] * wa[0] + le[1] * wa[1] + le[2] * wa[2] + le[3] * wa[3];
            #pragma unroll
            for (int off = 32; off > 0; off >>= 1) p += __shfl_xor(p, off, 64);
            if (lane == 0) ldot[l * 8 + pair] = p;
        }
    }
    __syncthreads();
    int c = t & 255, half = t >> 8;
    float bv = bf_s[c];
    float* xb = xtok + (size_t)b * 196 * 256 + c;
    for (int r = half; r < 196; r += 2) xb[(size_t)r * 256] = bv;
}

// -------- K3: lateral projection, 8 K-slices, bf16 pf direct-load, sw in epilogue --------
__global__ __launch_bounds__(256) void lateral_slice(
    const unsigned short* __restrict__ pf0, const unsigned short* __restrict__ pf1,
    const unsigned short* __restrict__ pf2, const unsigned short* __restrict__ pf3,
    const float* __restrict__ w0, const float* __restrict__ w1,
    const float* __restrict__ w2, const float* __restrict__ w3,
    const float* __restrict__ sw, float* __restrict__ xtok)
{
    const int sArr[8]    = {0, 1, 2, 2, 3, 3, 3, 3};
    const int koffArr[8] = {0, 0, 0, 512, 0, 512, 1024, 1536};
    const int klenArr[8] = {256, 512, 512, 512, 512, 512, 512, 512};
    int sl = blockIdx.y;
    int s = sArr[sl], koff = koffArr[sl], klen = klenArr[sl];
    const unsigned short* pf = (s == 0) ? pf0 : (s == 1) ? pf1 : (s == 2) ? pf2 : pf3;
    const float* W  = (s == 0) ? w0  : (s == 1) ? w1  : (s == 2) ? w2  : w3;

    int mt = blockIdx.x % 49, nt = blockIdx.x / 49;
    int m0 = mt * 32, n0 = nt * 64;
    __shared__ alignas(16) unsigned short As[1024];
    __shared__ alignas(16) unsigned short Bs[2048];
    int t = threadIdx.x, lane = t & 63, wid = t >> 6;
    int wm = wid >> 1, wn = wid & 1;
    f32x4 acc0 = {0, 0, 0, 0}, acc1 = {0, 0, 0, 0};

    int f = t & 63;
    int mA = m0 + ((t >> 6) & 1) * 16 + (f & 15);   // t<128
    int kbA = (f >> 4) * 8;
    int nB = n0 + (t >> 6) * 16 + (f & 15);
    int kbB = (f >> 4) * 8;

    unsigned short ark[8];
    float br[8];
    auto loadA = [&](int k0) {
        if (t < 128) {
            const unsigned short* base = pf + (size_t)(koff + k0 + kbA) * 1568 + mA;
            #pragma unroll
            for (int j = 0; j < 8; j++) ark[j] = base[(size_t)j * 1568];
        }
    };
    auto loadB = [&](int k0) {
        const float* base = W + (size_t)(koff + k0 + kbB) * 256 + nB;
        #pragma unroll
        for (int j = 0; j < 8; j++) br[j] = base[(size_t)j * 256];
    };

    loadA(0); loadB(0);
    for (int k0 = 0; k0 < klen; k0 += 32) {
        if (t < 128) {
            bshort8 v8;
            #pragma unroll
            for (int j = 0; j < 8; j++) v8[j] = (short)ark[j];
            *(bshort8*)&As[(((t >> 6) & 1) * 512 + f * 8)] = v8;
        }
        *(bshort8*)&Bs[((t >> 6) * 512 + f * 8)] = pack8(br);
        __syncthreads();
        if (k0 + 32 < klen) { loadA(k0 + 32); loadB(k0 + 32); }
        bshort8 av = *(const bshort8*)&As[wm * 512 + lane * 8];
        bshort8 bv0 = *(const bshort8*)&Bs[(wn * 2 + 0) * 512 + lane * 8];
        bshort8 bv1 = *(const bshort8*)&Bs[(wn * 2 + 1) * 512 + lane * 8];
        acc0 = mfma16(av, bv0, acc0);
        acc1 = mfma16(av, bv1, acc1);
        __syncthreads();
    }
    int col0 = n0 + wn * 32 + (lane & 15);
    int rbase = m0 + wm * 16 + ((lane >> 4) << 2);
    #pragma unroll
    for (int r = 0; r < 4; r++) {
        int m = rbase + r;
        float swv = sw[(m / 196) * 4 + s];
        atomicAdd(&xtok[(size_t)m * 256 + col0], acc0[r] * swv);
        atomicAdd(&xtok[(size_t)m * 256 + col0 + 16], acc1[r] * swv);
    }
}

// -------- generic bf16-MFMA GEMM (used for qkv only) --------
template <bool B_IS_KXN>
__global__ __launch_bounds__(256) void gemm_kernel(
    const float* __restrict__ Ab, int lda, long long sAy, long long sAz,
    const float* __restrict__ Bb, int ldb, long long sBy, long long sBz,
    float* __restrict__ Cb, int ldc, long long sCy, long long sCz,
    const float* __restrict__ bias, int M, int N, int K,
    float alpha, int mtiles)
{
    const float* A = Ab + blockIdx.y * sAy + blockIdx.z * sAz;
    const float* B = Bb + blockIdx.y * sBy + blockIdx.z * sBz;
    float* C = Cb + blockIdx.y * sCy + blockIdx.z * sCz;
    int mt = blockIdx.x % mtiles, nt = blockIdx.x / mtiles;
    int m0 = mt * 32, n0 = nt * 64;
    __shared__ alignas(16) unsigned short As[1024];
    __shared__ alignas(16) unsigned short Bs[2048];
    int t = threadIdx.x, lane = t & 63, wid = t >> 6;
    int wm = wid >> 1, wn = wid & 1;
    f32x4 acc0 = {0, 0, 0, 0}, acc1 = {0, 0, 0, 0};

    int f = t & 63;
    int mA = m0 + ((t >> 6) & 1) * 16 + (f & 15);   // t<128
    int kbA = (f >> 4) * 8;
    int nB = n0 + (t >> 6) * 16 + (f & 15);
    int kbB = (f >> 4) * 8;

    float ar[8], br[8];
    auto loadA = [&](int k0) {
        if (t < 128) {
            int kb = k0 + kbA;
            if (mA < M && kb + 8 <= K) {
                const float4* p = (const float4*)(A + (size_t)mA * lda + kb);
                float4 u = p[0], v = p[1];
                ar[0] = u.x; ar[1] = u.y; ar[2] = u.z; ar[3] = u.w;
                ar[4] = v.x; ar[5] = v.y; ar[6] = v.z; ar[7] = v.w;
            } else {
                #pragma unroll
                for (int j = 0; j < 8; j++) {
                    int k = kb + j;
                    ar[j] = (mA < M && k < K) ? A[(size_t)mA * lda + k] : 0.f;
                }
            }
        }
    };
    auto loadB = [&](int k0) {
        int kb = k0 + kbB;
        if constexpr (B_IS_KXN) {
            #pragma unroll
            for (int j = 0; j < 8; j++) {
                int k = kb + j;
                br[j] = (k < K && nB < N) ? B[(size_t)k * ldb + nB] : 0.f;
            }
        } else {
            if (nB < N && kb + 8 <= K) {
                const float4* p = (const float4*)(B + (size_t)nB * ldb + kb);
                float4 u = p[0], v = p[1];
                br[0] = u.x; br[1] = u.y; br[2] = u.z; br[3] = u.w;
                br[4] = v.x; br[5] = v.y; br[6] = v.z; br[7] = v.w;
            } else {
                #pragma unroll
                for (int j = 0; j < 8; j++) {
                    int k = kb + j;
                    br[j] = (nB < N && k < K) ? B[(size_t)nB * ldb + k] : 0.f;
                }
            }
        }
    };

    loadA(0); loadB(0);
    for (int k0 = 0; k0 < K; k0 += 32) {
        if (t < 128) *(bshort8*)&As[(((t >> 6) & 1) * 512 + f * 8)] = pack8(ar);
        *(bshort8*)&Bs[((t >> 6) * 512 + f * 8)] = pack8(br);
        __syncthreads();
        if (k0 + 32 < K) { loadA(k0 + 32); loadB(k0 + 32); }
        bshort8 av = *(const bshort8*)&As[wm * 512 + lane * 8];
        bshort8 bv0 = *(const bshort8*)&Bs[(wn * 2 + 0) * 512 + lane * 8];
        bshort8 bv1 = *(const bshort8*)&Bs[(wn * 2 + 1) * 512 + lane * 8];
        acc0 = mfma16(av, bv0, acc0);
        acc1 = mfma16(av, bv1, acc1);
        __syncthreads();
    }
    int col0 = n0 + wn * 32 + (lane & 15);
    int rbase = m0 + wm * 16 + ((lane >> 4) << 2);
    #pragma unroll
    for (int r = 0; r < 4; r++) {
        int m = rbase + r;
        if (m < M) {
            if (col0 < N) {
                float v = acc0[r] * alpha;
                if (bias) v += bias[col0];
                C[(size_t)m * ldc + col0] = v;
            }
            int c1 = col0 + 16;
            if (c1 < N) {
                float v = acc1[r] * alpha;
                if (bias) v += bias[c1];
                C[(size_t)m * ldc + c1] = v;
            }
        }
    }
}

// -------- fused attention: S = qk^T*scale, softmax, P@V — all in LDS per block --------
// grid (7 q-tiles, 8 heads, 8 batch); S-tile [32 x 256(pad)] f32 in LDS.
__global__ __launch_bounds__(256) void fused_attn(
    const float* __restrict__ qkv, float* __restrict__ xo)
{
    int mt = blockIdx.x, h = blockIdx.y, b = blockIdx.z;
    const float* Qb = qkv + (size_t)b * 150528 + h * 32;
    const float* Kb = Qb + 256;
    const float* Vb = Qb + 512;

    __shared__ alignas(16) unsigned short As[1024];
    __shared__ alignas(16) unsigned short Bs[2048];
    __shared__ float Ss[32 * 256];

    int t = threadIdx.x, lane = t & 63, wid = t >> 6;
    int wm = wid >> 1, wn = wid & 1;
    int f = t & 63;
    int m0 = mt * 32;

    // ---- stage A (q tile: 32 rows x K=32) ----
    if (t < 128) {
        float ar[8];
        int mA = m0 + ((t >> 6) & 1) * 16 + (f & 15);
        int kb = (f >> 4) * 8;
        if (mA < 196) {
            const float4* p = (const float4*)(Qb + (size_t)mA * 768 + kb);
            float4 u = p[0], v = p[1];
            ar[0] = u.x; ar[1] = u.y; ar[2] = u.z; ar[3] = u.w;
            ar[4] = v.x; ar[5] = v.y; ar[6] = v.z; ar[7] = v.w;
        } else {
            #pragma unroll
            for (int j = 0; j < 8; j++) ar[j] = 0.f;
        }
        *(bshort8*)&As[(((t >> 6) & 1) * 512 + f * 8)] = pack8(ar);
    }

    // ---- S phase: 4 groups of 64 keys ----
    {
        int nBl = (t >> 6) * 16 + (f & 15);
        int kbB = (f >> 4) * 8;
        float br[8];
        auto loadB = [&](int g) {
            int key = g * 64 + nBl;
            if (key < 196) {
                const float4* p = (const float4*)(Kb + (size_t)key * 768 + kbB);
                float4 u = p[0], v = p[1];
                br[0] = u.x; br[1] = u.y; br[2] = u.z; br[3] = u.w;
                br[4] = v.x; br[5] = v.y; br[6] = v.z; br[7] = v.w;
            } else {
                #pragma unroll
                for (int j = 0; j < 8; j++) br[j] = 0.f;
            }
        };
        loadB(0);
        for (int g = 0; g < 4; g++) {
            __syncthreads();                              // Bs reuse guard
            *(bshort8*)&Bs[((t >> 6) * 512 + f * 8)] = pack8(br);
            __syncthreads();
            if (g < 3) loadB(g + 1);
            f32x4 acc0 = {0, 0, 0, 0}, acc1 = {0, 0, 0, 0};
            bshort8 av = *(const bshort8*)&As[wm * 512 + lane * 8];
            bshort8 bv0 = *(const bshort8*)&Bs[(wn * 2 + 0) * 512 + lane * 8];
            bshort8 bv1 = *(const bshort8*)&Bs[(wn * 2 + 1) * 512 + lane * 8];
            acc0 = mfma16(av, bv0, acc0);
            acc1 = mfma16(av, bv1, acc1);
            int col0 = g * 64 + wn * 32 + (lane & 15);
            int rbase = wm * 16 + ((lane >> 4) << 2);
            #pragma unroll
            for (int r = 0; r < 4; r++) {
                Ss[(rbase + r) * 256 + col0]      = acc0[r] * 0.17677669529663687f;
                Ss[(rbase + r) * 256 + col0 + 16] = acc1[r] * 0.17677669529663687f;
            }
        }
    }
    __syncthreads();

    // ---- softmax rows (cols 0..195); zero pad cols 196..255 ----
    {
        #pragma unroll
        for (int i = 0; i < 8; i++) {
            float* p = Ss + (wid * 8 + i) * 256;
            float v0 = p[lane], v1 = p[64 + lane], v2 = p[128 + lane];
            float v3 = (lane < 4) ? p[192 + lane] : -1e30f;
            float mx = fmaxf(fmaxf(v0, v1), fmaxf(v2, v3));
            #pragma unroll
            for (int off = 32; off > 0; off >>= 1) mx = fmaxf(mx, __shfl_xor(mx, off, 64));
            float e0 = expf(v0 - mx), e1 = expf(v1 - mx), e2 = expf(v2 - mx);
            float e3 = (lane < 4) ? expf(v3 - mx) : 0.f;
            float sum = e0 + e1 + e2 + e3;
            #pragma unroll
            for (int off = 32; off > 0; off >>= 1) sum += __shfl_xor(sum, off, 64);
            float inv = 1.f / sum;
            p[lane] = e0 * inv;
            p[64 + lane] = e1 * inv;
            p[128 + lane] = e2 * inv;
            if (lane < 4) p[192 + lane] = e3 * inv;
            else          p[192 + lane] = 0.f;            // pad cols 196..255
        }
    }
    __syncthreads();

    // ---- PV: out[32,32] = P[32,256] @ V[256(pad),32] ----
    {
        f32x4 acc0 = {0, 0, 0, 0}, acc1 = {0, 0, 0, 0};
        int nBl = (t >> 6) * 16 + (f & 15);               // 0..63, valid <32
        int kbB = (f >> 4) * 8;
        int mAl = ((t >> 6) & 1) * 16 + (f & 15);
        int kbA = (f >> 4) * 8;
        float ar[8], br[8];
        auto loadA = [&](int k0) {
            if (t < 128) {
                #pragma unroll
                for (int j = 0; j < 8; j++) ar[j] = Ss[mAl * 256 + k0 + kbA + j];
            }
        };
        auto loadB = [&](int k0) {
            #pragma unroll
            for (int j = 0; j < 8; j++) {
                int k = k0 + kbB + j;
                br[j] = (k < 196 && nBl < 32) ? Vb[(size_t)k * 768 + nBl] : 0.f;
            }
        };
        loadA(0); loadB(0);
        for (int k0 = 0; k0 < 256; k0 += 32) {
            __syncthreads();                              // As/Bs reuse guard
            if (t < 128) *(bshort8*)&As[(((t >> 6) & 1) * 512 + f * 8)] = pack8(ar);
            *(bshort8*)&Bs[((t >> 6) * 512 + f * 8)] = pack8(br);
            __syncthreads();
            if (k0 + 32 < 256) { loadA(k0 + 32); loadB(k0 + 32); }
            bshort8 av = *(const bshort8*)&As[wm * 512 + lane * 8];
            bshort8 bv0 = *(const bshort8*)&Bs[(wn * 2 + 0) * 512 + lane * 8];
            bshort8 bv1 = *(const bshort8*)&Bs[(wn * 2 + 1) * 512 + lane * 8];
            acc0 = mfma16(av, bv0, acc0);
            acc1 = mfma16(av, bv1, acc1);
        }
        int col0 = wn * 32 + (lane & 15);
        int rbase = wm * 16 + ((lane >> 4) << 2);
        if (col0 < 32) {
            #pragma unroll
            for (int r = 0; r < 4; r++) {
                int m = m0 + rbase + r;
                if (m < 196) {
                    xo[((size_t)b * 196 + m) * 256 + h * 32 + col0]      = acc0[r];
                    xo[((size_t)b * 196 + m) * 256 + h * 32 + col0 + 16] = acc1[r];
                }
            }
        }
    }
}

// ================= tail, stage 1: one block per (b,h) — 32 blocks =================
__global__ __launch_bounds__(1024) void tail1(
    const float* __restrict__ xo, const float* __restrict__ proj_w,
    const float* __restrict__ proj_b,
    const float* __restrict__ gat_W, const float* __restrict__ lemb,
    const float* __restrict__ Wa, const float* __restrict__ ldot,
    float* __restrict__ atts, float* __restrict__ hm_g)
{
    int b = blockIdx.x >> 2, h = blockIdx.x & 3;
    int t = threadIdx.x, lane = t & 63, wv = t >> 6;
    __shared__ float red[1024];
    __shared__ float xm[256];
    __shared__ float gctx_s[256];
    __shared__ float gdot_s[2];
    __shared__ float s12h[160];
    __shared__ float am_s[80];
    __shared__ float av_s[256];

    {
        int c = t & 255, sl = t >> 8;
        const float* base = xo + ((size_t)b * 196 + sl * 49) * 256 + c;
        float s = 0.f;
        #pragma unroll 7
        for (int i = 0; i < 49; i++) s += base[(size_t)i * 256];
        red[t] = s;
    }
    if (t < 80) am_s[t] = 0.f;
    __syncthreads();
    if (t < 256) xm[t] = (red[t] + red[256 + t] + red[512 + t] + red[768 + t]) * (1.f / 196.f);
    __syncthreads();

    {
        int n = t & 255, ks = t >> 8;
        float acc = 0.f;
        const float* w = proj_w + (size_t)(ks * 64) * 256 + n;
        #pragma unroll 8
        for (int i = 0; i < 64; i++) acc += xm[ks * 64 + i] * w[(size_t)i * 256];
        red[t] = acc;
    }
    __syncthreads();
    if (t < 256) gctx_s[t] = proj_b[t] + red[t] + red[256 + t] + red[512 + t] + red[768 + t];
    __syncthreads();

    if (wv < 2) {
        int pair = h * 2 + wv;
        const float* wa = Wa + pair * 256 + lane * 4;
        float p = gctx_s[lane * 4] * wa[0] + gctx_s[lane * 4 + 1] * wa[1]
                + gctx_s[lane * 4 + 2] * wa[2] + gctx_s[lane * 4 + 3] * wa[3];
        #pragma unroll
        for (int off = 32; off > 0; off >>= 1) p += __shfl_xor(p, off, 64);
        if (lane == 0) gdot_s[wv] = p;
    }
    __syncthreads();
    if (t < 160) {
        int q = t / 80, l = t - q * 80;
        s12h[t] = ldot[l * 8 + h * 2 + q] + gdot_s[q];
    }
    __syncthreads();

    {
        #pragma unroll
        for (int rr = 0; rr < 5; rr++) {
            int i = rr * 16 + wv;
            float s1i = s12h[i];
            const float* s2 = s12h + 80;
            float v0 = s1i + s2[lane]; v0 = v0 > 0.f ? v0 : 0.2f * v0;
            float v1 = -1e30f;
            if (lane < 16) { v1 = s1i + s2[64 + lane]; v1 = v1 > 0.f ? v1 : 0.2f * v1; }
            float mx = fmaxf(v0, v1);
            #pragma unroll
            for (int off = 32; off > 0; off >>= 1) mx = fmaxf(mx, __shfl_xor(mx, off, 64));
            float e0 = expf(v0 - mx), e1 = (lane < 16) ? expf(v1 - mx) : 0.f;
            float sum = e0 + e1;
            #pragma unroll
            for (int off = 32; off > 0; off >>= 1) sum += __shfl_xor(sum, off, 64);
            float inv = 1.f / sum;
            float* orow = atts + (size_t)h * 51200 + b * 6400 + i * 80;
            float p0 = e0 * inv;
            orow[lane] = p0;
            atomicAdd(&am_s[lane], p0);
            if (lane < 16) {
                float p1 = e1 * inv;
                orow[64 + lane] = p1;
                atomicAdd(&am_s[64 + lane], p1);
            }
        }
    }
    __syncthreads();

    {
        int n = t & 255, ks = t >> 8;
        float acc = 0.f;
        const float* le = lemb + n;
        #pragma unroll 5
        for (int l = ks * 20; l < ks * 20 + 20; l++) acc += am_s[l] * le[(size_t)l * 256];
        red[t] = acc;
    }
    __syncthreads();
    if (t < 256)
        av_s[t] = (red[t] + red[256 + t] + red[512 + t] + red[768 + t]) * (1.f / 80.f)
                + gctx_s[t];
    __syncthreads();
    {
        int n = t & 255, ks = t >> 8;
        float acc = 0.f;
        const float* w = gat_W + (size_t)h * 65536 + (size_t)(ks * 64) * 256 + n;
        #pragma unroll 8
        for (int i = 0; i < 64; i++) acc += av_s[ks * 64 + i] * w[(size_t)i * 256];
        red[t] = acc;
    }
    __syncthreads();
    if (t < 256)
        hm_g[(b * 4 + h) * 256 + t] = red[t] + red[256 + t] + red[512 + t] + red[768 + t];
}

// ================= tail, stage 2: one block per b — 8 blocks =================
__global__ __launch_bounds__(1024) void tail2(
    const float* __restrict__ hm_g,
    const float* __restrict__ out_w, const float* __restrict__ out_b,
    const float* __restrict__ spec_w1, const float* __restrict__ spec_b1,
    const float* __restrict__ spec_w2, const float* __restrict__ spec_b2,
    const float* __restrict__ spat_w1, const float* __restrict__ spat_b1,
    const float* __restrict__ spat_w2, const float* __restrict__ spat_b2,
    const float* __restrict__ gate_w, const float* __restrict__ gate_b,
    const float* __restrict__ unc_w, const float* __restrict__ unc_b,
    float* __restrict__ out)
{
    int b = blockIdx.x, t = threadIdx.x;
    __shared__ float red[1024];
    __shared__ float as_s[256];
    __shared__ float hb_s[256];
    __shared__ float fv_s[320];

    {
        int n = t & 255, ks = t >> 8;
        float acc = 0.f;
        const float* hv = hm_g + b * 1024 + ks * 256;
        const float* w = out_w + (size_t)(ks * 256) * 256 + n;
        #pragma unroll 8
        for (int k = 0; k < 256; k++) acc += hv[k] * w[(size_t)k * 256];
        red[t] = acc;
    }
    __syncthreads();
    if (t < 256) as_s[t] = out_b[t] + red[t] + red[256 + t] + red[512 + t] + red[768 + t];
    __syncthreads();

    {
        int u = t & 255, ks = t >> 8;
        int which = u >> 7, oo = u & 127;
        const float* w1 = which ? spat_w1 : spec_w1;
        float acc = 0.f;
        #pragma unroll 8
        for (int i = 0; i < 64; i++) {
            int k = ks * 64 + i;
            acc += as_s[k] * w1[(size_t)k * 128 + oo];
        }
        red[t] = acc;
    }
    __syncthreads();
    if (t < 256) {
        int which = t >> 7, oo = t & 127;
        const float* b1 = which ? spat_b1 : spec_b1;
        hb_s[t] = fmaxf(red[t] + red[256 + t] + red[512 + t] + red[768 + t] + b1[oo], 0.f);
    }
    __syncthreads();

    if (t < 960) {
        int sub = t / 320, u = t - sub * 320;
        int head = u / 80, o = u - head * 80;
        const float* wp; const float* src; int K;
        if (head == 0)      { wp = spec_w2; src = hb_s;       K = 128; }
        else if (head == 1) { wp = spat_w2; src = hb_s + 128; K = 128; }
        else if (head == 2) { wp = gate_w;  src = as_s;       K = 256; }
        else                { wp = unc_w;   src = as_s;       K = 256; }
        int k0 = (K * sub) / 3, k1 = (K * (sub + 1)) / 3;
        float acc = 0.f;
        for (int k = k0; k < k1; k++) acc += src[k] * wp[(size_t)k * 80 + o];
        red[sub * 320 + u] = acc;
    }
    __syncthreads();
    if (t < 320) {
        int head = t / 80, o = t - head * 80;
        const float* bp = head == 0 ? spec_b2 : head == 1 ? spat_b2 : head == 2 ? gate_b : unc_b;
        fv_s[t] = red[t] + red[320 + t] + red[640 + t] + bp[o];
    }
    __syncthreads();

    if (t < 80) {
        float sp = fv_s[t], st2 = fv_s[80 + t], gz = fv_s[160 + t], uz = fv_s[240 + t];
        float g = 1.f / (1.f + expf(-gz));
        out[b * 80 + t] = g * sp + (1.f - g) * st2;
        out[640 + b * 80 + t] = sp;
        out[1280 + b * 80 + t] = st2;
        out[1920 + b * 80 + t] = g;
        red[t] = log1pf(expf(uz)) + 1.f;
    }
    __syncthreads();
    if (t == 0) {
        float s = 0.f;
        for (int l = 0; l < 80; l++) s += red[l];
        out[2560 + b] = 80.f / s;
    }
}

// ---------------- launcher ----------------
extern "C" void kernel_launch(void* const* d_in, const int* in_sizes, int n_in,
                              void* d_out, int out_size, void* d_ws, size_t ws_size,
                              hipStream_t stream)
{
    (void)in_sizes; (void)n_in; (void)out_size; (void)ws_size;
    const float* c2 = (const float*)d_in[0];
    const float* c3 = (const float*)d_in[1];
    const float* c4 = (const float*)d_in[2];
    const float* c5 = (const float*)d_in[3];
    const float* lat_w0 = (const float*)d_in[4];
    const float* lat_b0 = (const float*)d_in[5];
    const float* lat_w1 = (const float*)d_in[6];
    const float* lat_b1 = (const float*)d_in[7];
    const float* lat_w2 = (const float*)d_in[8];
    const float* lat_b2 = (const float*)d_in[9];
    const float* lat_w3 = (const float*)d_in[10];
    const float* lat_b3 = (const float*)d_in[11];
    const float* sp_w1 = (const float*)d_in[12];
    const float* sp_b1 = (const float*)d_in[13];
    const float* sp_w2 = (const float*)d_in[14];
    const float* sp_b2 = (const float*)d_in[15];
    const float* qkv_w = (const float*)d_in[16];
    const float* qkv_b = (const float*)d_in[17];
    const float* proj_w = (const float*)d_in[18];
    const float* proj_b = (const float*)d_in[19];
    const float* gat_W = (const float*)d_in[20];
    const float* gat_a = (const float*)d_in[21];
    const float* out_w = (const float*)d_in[22];
    const float* out_b = (const float*)d_in[23];
    const float* label_emb = (const float*)d_in[24];
    const float* spec_w1 = (const float*)d_in[25];
    const float* spec_b1 = (const float*)d_in[26];
    const float* spec_w2 = (const float*)d_in[27];
    const float* spec_b2 = (const float*)d_in[28];
    const float* spat_w1 = (const float*)d_in[29];
    const float* spat_b1 = (const float*)d_in[30];
    const float* spat_w2 = (const float*)d_in[31];
    const float* spat_b2 = (const float*)d_in[32];
    const float* gate_w = (const float*)d_in[33];
    const float* gate_b = (const float*)d_in[34];
    const float* unc_w = (const float*)d_in[35];
    const float* unc_b = (const float*)d_in[36];

    float* out = (float*)d_out;
    float* ws = (float*)d_ws;

    // workspace layout (floats); pf buffers now bf16 (ushort) in same regions
    unsigned short* pf0 = (unsigned short*)(ws + 0);        // 401408 elems
    unsigned short* pf1 = (unsigned short*)(ws + 401408);   // 802816
    unsigned short* pf2 = (unsigned short*)(ws + 1204224);  // 1605632
    unsigned short* pf3 = (unsigned short*)(ws + 2809856);  // 3211264 (ends 6021120)
    float* pooled = ws + 6021120;  // 16384  -> 6037504
    float* swpart = ws + 6039552;  // 32768  -> 6072320
    float* Wa     = ws + 6072320;  // 2048   -> 6074368
    float* ldot   = ws + 6074368;  // 640    -> 6075008
    float* qkv    = ws + 0;        // reuses pf0/pf1 region (dead after lateral)
    float* xo     = ws + 3662848;  // 401408 -> 4064256
    float* hm_g   = ws + 4253696;  // 8192   -> 4261888
    float* xtok   = ws + 6106112;  // 401408 -> 6507520

    float* swp  = out + 2568;  // sw [8,4] (output 5)
    float* atts = out + 2600;  // atts [4,8,80,80] (output 6)

    // 1. ALL pools (bf16 out) + c5 mean in one dispatch
    pool_all<<<27616, 256, 0, stream>>>(c2, c3, c4, c5, pf0, pf1, pf2, pf3, pooled);
    // 2. scale-weight MLP partials + hoisted Wa (16 extra blocks)
    sw_part<<<dim3(8, 10), 512, 0, stream>>>(pooled, sp_w1, swpart, gat_W, gat_a, Wa);
    // 2b. finish sw MLP + bias-init xtok + hoisted ldot
    sw_fin<<<8, 512, 0, stream>>>(swpart, sp_b1, sp_w2, sp_b2,
                                  lat_b0, lat_b1, lat_b2, lat_b3,
                                  label_emb, Wa, swp, xtok, ldot);
    // 3. lateral projection (bf16 pf direct-load, sw in epilogue) -> xtok [1568,256]
    lateral_slice<<<dim3(196, 8), 256, 0, stream>>>(pf0, pf1, pf2, pf3,
                                                    lat_w0, lat_w1, lat_w2, lat_w3,
                                                    swp, xtok);
    // 4. qkv = x @ qkv_w + qkv_b : [1568,768]
    gemm_kernel<true><<<dim3(49 * 12, 1, 1), 256, 0, stream>>>(
        xtok, 256, 0, 0, qkv_w, 768, 0, 0, qkv, 768, 0, 0,
        qkv_b, 1568, 768, 256, 1.f, 49);
    // 5. fused attention: S, softmax, PV in one kernel -> xo [1568,256]
    fused_attn<<<dim3(7, 8, 8), 256, 0, stream>>>(qkv, xo);
    // 6. tail stage 1: per (b,h) — gctx/s12/softmax/av/hm (32 blocks)
    tail1<<<32, 1024, 0, stream>>>(xo, proj_w, proj_b, gat_W, label_emb,
                                   Wa, ldot, atts, hm_g);
    // 7. tail stage 2: per b — a_s/MLPs/heads/combine (8 blocks)
    tail2<<<8, 1024, 0, stream>>>(hm_g, out_w, out_b,
                                  spec_w1, spec_b1, spec_w2, spec_b2,
                                  spat_w1, spat_b1, spat_w2, spat_b2,
                                  gate_w, gate_b, unc_w, unc_b, out);
}

// Round 7
// 460.700 us; speedup vs baseline: 1.4343x; 1.0725x over previous
//
#include <hip/hip_runtime.h>
#include <math.h>

typedef __attribute__((ext_vector_type(8))) short bshort8;
typedef __attribute__((ext_vector_type(4))) float f32x4;

#define DI __device__ __forceinline__

DI unsigned short f2bf(float x) {
    unsigned int u = __builtin_bit_cast(unsigned int, x);
    u += 0x7fffu + ((u >> 16) & 1u);
    return (unsigned short)(u >> 16);
}

DI bshort8 pack8(const float* v) {
    bshort8 r;
    #pragma unroll
    for (int j = 0; j < 8; j++) r[j] = (short)f2bf(v[j]);
    return r;
}

DI f32x4 mfma16(bshort8 a, bshort8 b, f32x4 c) {
    return __builtin_amdgcn_mfma_f32_16x16x32_bf16(a, b, c, 0, 0, 0);
}

// ---- composite (bilinear resize N->112, align_corners=False) + 8x8 avgpool stencils ----
__device__ const float W14[14][3] = {
    {0.875f, 0.125f, 0.f},
    {0.125f, 0.75f, 0.125f}, {0.125f, 0.75f, 0.125f}, {0.125f, 0.75f, 0.125f},
    {0.125f, 0.75f, 0.125f}, {0.125f, 0.75f, 0.125f}, {0.125f, 0.75f, 0.125f},
    {0.125f, 0.75f, 0.125f}, {0.125f, 0.75f, 0.125f}, {0.125f, 0.75f, 0.125f},
    {0.125f, 0.75f, 0.125f}, {0.125f, 0.75f, 0.125f}, {0.125f, 0.75f, 0.125f},
    {0.125f, 0.875f, 0.f}};
__device__ const float W28[14][4] = {
    {0.5f, 0.4375f, 0.0625f, 0.f},
    {0.0625f, 0.4375f, 0.4375f, 0.0625f}, {0.0625f, 0.4375f, 0.4375f, 0.0625f},
    {0.0625f, 0.4375f, 0.4375f, 0.0625f}, {0.0625f, 0.4375f, 0.4375f, 0.0625f},
    {0.0625f, 0.4375f, 0.4375f, 0.0625f}, {0.0625f, 0.4375f, 0.4375f, 0.0625f},
    {0.0625f, 0.4375f, 0.4375f, 0.0625f}, {0.0625f, 0.4375f, 0.4375f, 0.0625f},
    {0.0625f, 0.4375f, 0.4375f, 0.0625f}, {0.0625f, 0.4375f, 0.4375f, 0.0625f},
    {0.0625f, 0.4375f, 0.4375f, 0.0625f}, {0.0625f, 0.4375f, 0.4375f, 0.0625f},
    {0.0625f, 0.4375f, 0.5f, 0.f}};
__device__ const float W56[14][6] = {
    {0.25f, 0.25f, 0.25f, 0.21875f, 0.03125f, 0.f},
    {0.03125f, 0.21875f, 0.25f, 0.25f, 0.21875f, 0.03125f},
    {0.03125f, 0.21875f, 0.25f, 0.25f, 0.21875f, 0.03125f},
    {0.03125f, 0.21875f, 0.25f, 0.25f, 0.21875f, 0.03125f},
    {0.03125f, 0.21875f, 0.25f, 0.25f, 0.21875f, 0.03125f},
    {0.03125f, 0.21875f, 0.25f, 0.25f, 0.21875f, 0.03125f},
    {0.03125f, 0.21875f, 0.25f, 0.25f, 0.21875f, 0.03125f},
    {0.03125f, 0.21875f, 0.25f, 0.25f, 0.21875f, 0.03125f},
    {0.03125f, 0.21875f, 0.25f, 0.25f, 0.21875f, 0.03125f},
    {0.03125f, 0.21875f, 0.25f, 0.25f, 0.21875f, 0.03125f},
    {0.03125f, 0.21875f, 0.25f, 0.25f, 0.21875f, 0.03125f},
    {0.03125f, 0.21875f, 0.25f, 0.25f, 0.21875f, 0.03125f},
    {0.03125f, 0.21875f, 0.25f, 0.25f, 0.21875f, 0.03125f},
    {0.03125f, 0.21875f, 0.25f, 0.25f, 0.25f, 0.f}};

// -------- c2 path (N=112): direct 16B vector loads, 8x8 non-overlap mean --------
DI void pool_body112(const float* __restrict__ src, unsigned short* __restrict__ dst,
                     unsigned blk, unsigned t)
{
    unsigned id = blk * 256u + t;
    unsigned p = id / 196u;
    unsigned r = id - p * 196u;
    unsigned ti = r / 14u, tj = r - ti * 14u;
    unsigned b = p >> 8, cin = p & 255u;
    const float* plane = src + (size_t)p * 12544;
    const float4* p4 = (const float4*)(plane + (size_t)(ti * 8) * 112 + tj * 8);
    float4 rv[16];
    #pragma unroll
    for (int i = 0; i < 8; i++) { rv[2 * i] = p4[i * 28]; rv[2 * i + 1] = p4[i * 28 + 1]; }
    float acc = 0.f;
    #pragma unroll
    for (int i = 0; i < 16; i++) acc += (rv[i].x + rv[i].y) + (rv[i].z + rv[i].w);
    dst[(size_t)cin * 1568 + b * 196 + r] = f2bf(acc * (1.f / 64.f));
}

// -------- K1: all pools + c5 mean; LDS-staged planes for N=56/28/14 --------
// grid: 1568 (c2) + 4096 (c3 planes) + 8192 (c4 planes) + 4096 (c5 4-plane groups)
__global__ __launch_bounds__(256) void pool_all(
    const float* __restrict__ c2, const float* __restrict__ c3,
    const float* __restrict__ c4, const float* __restrict__ c5,
    unsigned short* __restrict__ pf0, unsigned short* __restrict__ pf1,
    unsigned short* __restrict__ pf2, unsigned short* __restrict__ pf3,
    float* __restrict__ pooled)
{
    __shared__ alignas(16) float ls[3136];
    unsigned bx = blockIdx.x, t = threadIdx.x;

    if (bx < 1568u) {                       // ---- c2: N=112 direct ----
        pool_body112(c2, pf0, bx, t);
        return;
    }
    if (bx < 5664u) {                       // ---- c3: N=56, block per plane ----
        unsigned p = bx - 1568u;
        unsigned b = p >> 9, cin = p & 511u;
        const float* plane = c3 + (size_t)p * 3136;
        float4* l4 = (float4*)ls;
        const float4* s4 = (const float4*)plane;
        for (int i = t; i < 784; i += 256) l4[i] = s4[i];
        __syncthreads();
        if (t < 196) {
            int ti = t / 14, tj = t - ti * 14;
            int hs = 4 * ti - 1; if (hs < 0) hs = 0;
            int ws = 4 * tj - 1; if (ws < 0) ws = 0;
            float acc = 0.f;
            #pragma unroll
            for (int i = 0; i < 6; i++) {
                int hi = hs + i; if (hi > 55) hi = 55;
                const float* row = ls + hi * 56;
                float rs = 0.f;
                #pragma unroll
                for (int j = 0; j < 6; j++) {
                    int wj = ws + j; if (wj > 55) wj = 55;
                    rs += W56[tj][j] * row[wj];
                }
                acc += W56[ti][i] * rs;
            }
            pf1[(size_t)cin * 1568 + b * 196 + t] = f2bf(acc);
        }
        return;
    }
    if (bx < 13856u) {                      // ---- c4: N=28, block per plane ----
        unsigned p = bx - 5664u;
        unsigned b = p >> 10, cin = p & 1023u;
        const float* plane = c4 + (size_t)p * 784;
        float4* l4 = (float4*)ls;
        const float4* s4 = (const float4*)plane;
        if (t < 196) l4[t] = s4[t];
        __syncthreads();
        if (t < 196) {
            int ti = t / 14, tj = t - ti * 14;
            int hs = 2 * ti - 1; if (hs < 0) hs = 0;
            int ws = 2 * tj - 1; if (ws < 0) ws = 0;
            float acc = 0.f;
            #pragma unroll
            for (int i = 0; i < 4; i++) {
                int hi = hs + i; if (hi > 27) hi = 27;
                const float* row = ls + hi * 28;
                float rs = 0.f;
                #pragma unroll
                for (int j = 0; j < 4; j++) {
                    int wj = ws + j; if (wj > 27) wj = 27;
                    rs += W28[tj][j] * row[wj];
                }
                acc += W28[ti][i] * rs;
            }
            pf2[(size_t)cin * 1568 + b * 196 + t] = f2bf(acc);
        }
        return;
    }
    {                                       // ---- c5: N=14, wave per plane + fused mean ----
        unsigned g = bx - 13856u;
        int wid = t >> 6, lane = t & 63;
        unsigned p = g * 4 + wid;
        unsigned b = p >> 11, cin = p & 2047u;
        const float* plane = c5 + (size_t)p * 196;
        float a0 = plane[lane];
        float a1 = plane[64 + lane];
        float a2 = plane[128 + lane];
        float a3 = (lane < 4) ? plane[192 + lane] : 0.f;
        float* lw = ls + wid * 200;
        lw[lane] = a0; lw[64 + lane] = a1; lw[128 + lane] = a2;
        if (lane < 4) lw[192 + lane] = a3;
        float v = a0 + a1 + a2 + a3;
        #pragma unroll
        for (int off = 32; off > 0; off >>= 1) v += __shfl_xor(v, off, 64);
        if (lane == 0) pooled[p] = v * (1.f / 196.f);
        __syncthreads();
        unsigned short* dst = pf3 + (size_t)cin * 1568 + b * 196;
        #pragma unroll
        for (int rr = 0; rr < 4; rr++) {
            int r = rr * 64 + lane;
            if (r < 196) {
                int ti = r / 14, tj = r - ti * 14;
                int hs = ti - 1; if (hs < 0) hs = 0;
                int ws = tj - 1; if (ws < 0) ws = 0;
                float acc = 0.f;
                #pragma unroll
                for (int i = 0; i < 3; i++) {
                    int hi = hs + i; if (hi > 13) hi = 13;
                    const float* row = lw + hi * 14;
                    float rs = 0.f;
                    #pragma unroll
                    for (int j = 0; j < 3; j++) {
                        int wj = ws + j; if (wj > 13) wj = 13;
                        rs += W14[tj][j] * row[wj];
                    }
                    acc += W14[ti][i] * rs;
                }
                dst[r] = f2bf(acc);
            }
        }
    }
}

// -------- K2a: partial GEMV for sw MLP layer 1 (split-K) + hoisted Wa (y>=8) --------
__global__ __launch_bounds__(512) void sw_part(
    const float* __restrict__ pooled, const float* __restrict__ sp_w1,
    float* __restrict__ partial,
    const float* __restrict__ gat_W, const float* __restrict__ gat_a,
    float* __restrict__ Wa)
{
    int t = threadIdx.x;
    if (blockIdx.y >= 8) {
        int e = (blockIdx.y - 8) * 8 + blockIdx.x;   // [0,16)
        int h = e >> 2, q = e & 3;
        __shared__ float a1[256], a2[256];
        if (t < 256) { a1[t] = gat_a[h * 512 + t]; a2[t] = gat_a[h * 512 + 256 + t]; }
        __syncthreads();
        int w = t >> 6, lane = t & 63;
        #pragma unroll
        for (int ci = 0; ci < 8; ci++) {
            int c = q * 64 + w * 8 + ci;
            const float* row = gat_W + (size_t)h * 65536 + (size_t)c * 256;
            float p1 = 0.f, p2 = 0.f;
            #pragma unroll
            for (int jj = 0; jj < 4; jj++) {
                float v = row[lane + 64 * jj];
                p1 += v * a1[lane + 64 * jj];
                p2 += v * a2[lane + 64 * jj];
            }
            #pragma unroll
            for (int off = 32; off > 0; off >>= 1) {
                p1 += __shfl_xor(p1, off, 64);
                p2 += __shfl_xor(p2, off, 64);
            }
            if (lane == 0) { Wa[h * 512 + c] = p1; Wa[h * 512 + 256 + c] = p2; }
        }
        return;
    }
    int b = blockIdx.x, kc = blockIdx.y;
    __shared__ float ps[256];
    if (t < 256) ps[t] = pooled[b * 2048 + kc * 256 + t];
    __syncthreads();
    float acc = 0.f;
    const float* w = sp_w1 + (size_t)(kc * 256) * 512 + t;
    #pragma unroll 8
    for (int c = 0; c < 256; c++) acc += ps[c] * w[(size_t)c * 512];
    partial[((size_t)b * 8 + kc) * 512 + t] = acc;
}

// -------- K2b: finish sw MLP + bias-init xtok + hoisted ldot = lemb @ Wa^T --------
__global__ __launch_bounds__(512) void sw_fin(
    const float* __restrict__ partial, const float* __restrict__ sp_b1,
    const float* __restrict__ sp_w2, const float* __restrict__ sp_b2,
    const float* __restrict__ lb0, const float* __restrict__ lb1,
    const float* __restrict__ lb2, const float* __restrict__ lb3,
    const float* __restrict__ lemb, const float* __restrict__ Wa,
    float* __restrict__ sw_out, float* __restrict__ xtok,
    float* __restrict__ ldot)
{
    int b = blockIdx.x, t = threadIdx.x;
    __shared__ float h[512];
    __shared__ float s4s[4];
    __shared__ float swl[4];
    __shared__ float bf_s[256];
    float a = sp_b1[t];
    #pragma unroll
    for (int kc = 0; kc < 8; kc++) a += partial[((size_t)b * 8 + kc) * 512 + t];
    h[t] = fmaxf(a, 0.f);
    __syncthreads();
    int wv = t >> 6, lane = t & 63;
    if (wv < 4) {
        float acc = 0.f;
        #pragma unroll
        for (int i = 0; i < 8; i++) {
            int idx = lane + 64 * i;
            acc += h[idx] * sp_w2[idx * 4 + wv];
        }
        #pragma unroll
        for (int off = 32; off > 0; off >>= 1) acc += __shfl_xor(acc, off, 64);
        if (lane == 0) s4s[wv] = acc + sp_b2[wv];
    }
    __syncthreads();
    if (t == 0) {
        float mx = fmaxf(fmaxf(s4s[0], s4s[1]), fmaxf(s4s[2], s4s[3]));
        float e0 = expf(s4s[0] - mx), e1 = expf(s4s[1] - mx);
        float e2 = expf(s4s[2] - mx), e3 = expf(s4s[3] - mx);
        float inv = 1.f / (e0 + e1 + e2 + e3);
        swl[0] = e0 * inv; swl[1] = e1 * inv; swl[2] = e2 * inv; swl[3] = e3 * inv;
        for (int o = 0; o < 4; o++) sw_out[b * 4 + o] = swl[o];
    }
    __syncthreads();
    if (t < 256)
        bf_s[t] = swl[0] * lb0[t] + swl[1] * lb1[t] + swl[2] * lb2[t] + swl[3] * lb3[t];
    // hoisted: ldot[l][pair] = dot(lemb[l], Wa[pair]); block b handles l = 10b..10b+9
    {
        int pair = t >> 6;
        #pragma unroll
        for (int r = 0; r < 10; r++) {
            int l = b * 10 + r;
            const float* le = lemb + l * 256 + lane * 4;
            const float* wa = Wa + pair * 256 + lane * 4;
            float p = le[0] * wa[0] + le[1] * wa[1] + le[2] * wa[2] + le[3] * wa[3];
            #pragma unroll
            for (int off = 32; off > 0; off >>= 1) p += __shfl_xor(p, off, 64);
            if (lane == 0) ldot[l * 8 + pair] = p;
        }
    }
    __syncthreads();
    int c = t & 255, half = t >> 8;
    float bv = bf_s[c];
    float* xb = xtok + (size_t)b * 196 * 256 + c;
    for (int r = half; r < 196; r += 2) xb[(size_t)r * 256] = bv;
}

// -------- K3: lateral projection, 8 K-slices, bf16 pf direct-load, sw in epilogue --------
__global__ __launch_bounds__(256) void lateral_slice(
    const unsigned short* __restrict__ pf0, const unsigned short* __restrict__ pf1,
    const unsigned short* __restrict__ pf2, const unsigned short* __restrict__ pf3,
    const float* __restrict__ w0, const float* __restrict__ w1,
    const float* __restrict__ w2, const float* __restrict__ w3,
    const float* __restrict__ sw, float* __restrict__ xtok)
{
    const int sArr[8]    = {0, 1, 2, 2, 3, 3, 3, 3};
    const int koffArr[8] = {0, 0, 0, 512, 0, 512, 1024, 1536};
    const int klenArr[8] = {256, 512, 512, 512, 512, 512, 512, 512};
    int sl = blockIdx.y;
    int s = sArr[sl], koff = koffArr[sl], klen = klenArr[sl];
    const unsigned short* pf = (s == 0) ? pf0 : (s == 1) ? pf1 : (s == 2) ? pf2 : pf3;
    const float* W  = (s == 0) ? w0  : (s == 1) ? w1  : (s == 2) ? w2  : w3;

    int mt = blockIdx.x % 49, nt = blockIdx.x / 49;
    int m0 = mt * 32, n0 = nt * 64;
    __shared__ alignas(16) unsigned short As[1024];
    __shared__ alignas(16) unsigned short Bs[2048];
    int t = threadIdx.x, lane = t & 63, wid = t >> 6;
    int wm = wid >> 1, wn = wid & 1;
    f32x4 acc0 = {0, 0, 0, 0}, acc1 = {0, 0, 0, 0};

    int f = t & 63;
    int mA = m0 + ((t >> 6) & 1) * 16 + (f & 15);   // t<128
    int kbA = (f >> 4) * 8;
    int nB = n0 + (t >> 6) * 16 + (f & 15);
    int kbB = (f >> 4) * 8;

    unsigned short ark[8];
    float br[8];
    auto loadA = [&](int k0) {
        if (t < 128) {
            const unsigned short* base = pf + (size_t)(koff + k0 + kbA) * 1568 + mA;
            #pragma unroll
            for (int j = 0; j < 8; j++) ark[j] = base[(size_t)j * 1568];
        }
    };
    auto loadB = [&](int k0) {
        const float* base = W + (size_t)(koff + k0 + kbB) * 256 + nB;
        #pragma unroll
        for (int j = 0; j < 8; j++) br[j] = base[(size_t)j * 256];
    };

    loadA(0); loadB(0);
    for (int k0 = 0; k0 < klen; k0 += 32) {
        if (t < 128) {
            bshort8 v8;
            #pragma unroll
            for (int j = 0; j < 8; j++) v8[j] = (short)ark[j];
            *(bshort8*)&As[(((t >> 6) & 1) * 512 + f * 8)] = v8;
        }
        *(bshort8*)&Bs[((t >> 6) * 512 + f * 8)] = pack8(br);
        __syncthreads();
        if (k0 + 32 < klen) { loadA(k0 + 32); loadB(k0 + 32); }
        bshort8 av = *(const bshort8*)&As[wm * 512 + lane * 8];
        bshort8 bv0 = *(const bshort8*)&Bs[(wn * 2 + 0) * 512 + lane * 8];
        bshort8 bv1 = *(const bshort8*)&Bs[(wn * 2 + 1) * 512 + lane * 8];
        acc0 = mfma16(av, bv0, acc0);
        acc1 = mfma16(av, bv1, acc1);
        __syncthreads();
    }
    int col0 = n0 + wn * 32 + (lane & 15);
    int rbase = m0 + wm * 16 + ((lane >> 4) << 2);
    #pragma unroll
    for (int r = 0; r < 4; r++) {
        int m = rbase + r;
        float swv = sw[(m / 196) * 4 + s];
        atomicAdd(&xtok[(size_t)m * 256 + col0], acc0[r] * swv);
        atomicAdd(&xtok[(size_t)m * 256 + col0 + 16], acc1[r] * swv);
    }
}

// -------- generic bf16-MFMA GEMM (used for qkv only) --------
template <bool B_IS_KXN>
__global__ __launch_bounds__(256) void gemm_kernel(
    const float* __restrict__ Ab, int lda, long long sAy, long long sAz,
    const float* __restrict__ Bb, int ldb, long long sBy, long long sBz,
    float* __restrict__ Cb, int ldc, long long sCy, long long sCz,
    const float* __restrict__ bias, int M, int N, int K,
    float alpha, int mtiles)
{
    const float* A = Ab + blockIdx.y * sAy + blockIdx.z * sAz;
    const float* B = Bb + blockIdx.y * sBy + blockIdx.z * sBz;
    float* C = Cb + blockIdx.y * sCy + blockIdx.z * sCz;
    int mt = blockIdx.x % mtiles, nt = blockIdx.x / mtiles;
    int m0 = mt * 32, n0 = nt * 64;
    __shared__ alignas(16) unsigned short As[1024];
    __shared__ alignas(16) unsigned short Bs[2048];
    int t = threadIdx.x, lane = t & 63, wid = t >> 6;
    int wm = wid >> 1, wn = wid & 1;
    f32x4 acc0 = {0, 0, 0, 0}, acc1 = {0, 0, 0, 0};

    int f = t & 63;
    int mA = m0 + ((t >> 6) & 1) * 16 + (f & 15);   // t<128
    int kbA = (f >> 4) * 8;
    int nB = n0 + (t >> 6) * 16 + (f & 15);
    int kbB = (f >> 4) * 8;

    float ar[8], br[8];
    auto loadA = [&](int k0) {
        if (t < 128) {
            int kb = k0 + kbA;
            if (mA < M && kb + 8 <= K) {
                const float4* p = (const float4*)(A + (size_t)mA * lda + kb);
                float4 u = p[0], v = p[1];
                ar[0] = u.x; ar[1] = u.y; ar[2] = u.z; ar[3] = u.w;
                ar[4] = v.x; ar[5] = v.y; ar[6] = v.z; ar[7] = v.w;
            } else {
                #pragma unroll
                for (int j = 0; j < 8; j++) {
                    int k = kb + j;
                    ar[j] = (mA < M && k < K) ? A[(size_t)mA * lda + k] : 0.f;
                }
            }
        }
    };
    auto loadB = [&](int k0) {
        int kb = k0 + kbB;
        if constexpr (B_IS_KXN) {
            #pragma unroll
            for (int j = 0; j < 8; j++) {
                int k = kb + j;
                br[j] = (k < K && nB < N) ? B[(size_t)k * ldb + nB] : 0.f;
            }
        } else {
            if (nB < N && kb + 8 <= K) {
                const float4* p = (const float4*)(B + (size_t)nB * ldb + kb);
                float4 u = p[0], v = p[1];
                br[0] = u.x; br[1] = u.y; br[2] = u.z; br[3] = u.w;
                br[4] = v.x; br[5] = v.y; br[6] = v.z; br[7] = v.w;
            } else {
                #pragma unroll
                for (int j = 0; j < 8; j++) {
                    int k = kb + j;
                    br[j] = (nB < N && k < K) ? B[(size_t)nB * ldb + k] : 0.f;
                }
            }
        }
    };

    loadA(0); loadB(0);
    for (int k0 = 0; k0 < K; k0 += 32) {
        if (t < 128) *(bshort8*)&As[(((t >> 6) & 1) * 512 + f * 8)] = pack8(ar);
        *(bshort8*)&Bs[((t >> 6) * 512 + f * 8)] = pack8(br);
        __syncthreads();
        if (k0 + 32 < K) { loadA(k0 + 32); loadB(k0 + 32); }
        bshort8 av = *(const bshort8*)&As[wm * 512 + lane * 8];
        bshort8 bv0 = *(const bshort8*)&Bs[(wn * 2 + 0) * 512 + lane * 8];
        bshort8 bv1 = *(const bshort8*)&Bs[(wn * 2 + 1) * 512 + lane * 8];
        acc0 = mfma16(av, bv0, acc0);
        acc1 = mfma16(av, bv1, acc1);
        __syncthreads();
    }
    int col0 = n0 + wn * 32 + (lane & 15);
    int rbase = m0 + wm * 16 + ((lane >> 4) << 2);
    #pragma unroll
    for (int r = 0; r < 4; r++) {
        int m = rbase + r;
        if (m < M) {
            if (col0 < N) {
                float v = acc0[r] * alpha;
                if (bias) v += bias[col0];
                C[(size_t)m * ldc + col0] = v;
            }
            int c1 = col0 + 16;
            if (c1 < N) {
                float v = acc1[r] * alpha;
                if (bias) v += bias[c1];
                C[(size_t)m * ldc + c1] = v;
            }
        }
    }
}

// -------- fused attention: S = qk^T*scale, softmax, P@V — all in LDS per block --------
__global__ __launch_bounds__(256) void fused_attn(
    const float* __restrict__ qkv, float* __restrict__ xo)
{
    int mt = blockIdx.x, h = blockIdx.y, b = blockIdx.z;
    const float* Qb = qkv + (size_t)b * 150528 + h * 32;
    const float* Kb = Qb + 256;
    const float* Vb = Qb + 512;

    __shared__ alignas(16) unsigned short As[1024];
    __shared__ alignas(16) unsigned short Bs[2048];
    __shared__ float Ss[32 * 256];

    int t = threadIdx.x, lane = t & 63, wid = t >> 6;
    int wm = wid >> 1, wn = wid & 1;
    int f = t & 63;
    int m0 = mt * 32;

    // ---- stage A (q tile: 32 rows x K=32) ----
    if (t < 128) {
        float ar[8];
        int mA = m0 + ((t >> 6) & 1) * 16 + (f & 15);
        int kb = (f >> 4) * 8;
        if (mA < 196) {
            const float4* p = (const float4*)(Qb + (size_t)mA * 768 + kb);
            float4 u = p[0], v = p[1];
            ar[0] = u.x; ar[1] = u.y; ar[2] = u.z; ar[3] = u.w;
            ar[4] = v.x; ar[5] = v.y; ar[6] = v.z; ar[7] = v.w;
        } else {
            #pragma unroll
            for (int j = 0; j < 8; j++) ar[j] = 0.f;
        }
        *(bshort8*)&As[(((t >> 6) & 1) * 512 + f * 8)] = pack8(ar);
    }

    // ---- S phase: 4 groups of 64 keys ----
    {
        int nBl = (t >> 6) * 16 + (f & 15);
        int kbB = (f >> 4) * 8;
        float br[8];
        auto loadB = [&](int g) {
            int key = g * 64 + nBl;
            if (key < 196) {
                const float4* p = (const float4*)(Kb + (size_t)key * 768 + kbB);
                float4 u = p[0], v = p[1];
                br[0] = u.x; br[1] = u.y; br[2] = u.z; br[3] = u.w;
                br[4] = v.x; br[5] = v.y; br[6] = v.z; br[7] = v.w;
            } else {
                #pragma unroll
                for (int j = 0; j < 8; j++) br[j] = 0.f;
            }
        };
        loadB(0);
        for (int g = 0; g < 4; g++) {
            __syncthreads();                              // Bs reuse guard
            *(bshort8*)&Bs[((t >> 6) * 512 + f * 8)] = pack8(br);
            __syncthreads();
            if (g < 3) loadB(g + 1);
            f32x4 acc0 = {0, 0, 0, 0}, acc1 = {0, 0, 0, 0};
            bshort8 av = *(const bshort8*)&As[wm * 512 + lane * 8];
            bshort8 bv0 = *(const bshort8*)&Bs[(wn * 2 + 0) * 512 + lane * 8];
            bshort8 bv1 = *(const bshort8*)&Bs[(wn * 2 + 1) * 512 + lane * 8];
            acc0 = mfma16(av, bv0, acc0);
            acc1 = mfma16(av, bv1, acc1);
            int col0 = g * 64 + wn * 32 + (lane & 15);
            int rbase = wm * 16 + ((lane >> 4) << 2);
            #pragma unroll
            for (int r = 0; r < 4; r++) {
                Ss[(rbase + r) * 256 + col0]      = acc0[r] * 0.17677669529663687f;
                Ss[(rbase + r) * 256 + col0 + 16] = acc1[r] * 0.17677669529663687f;
            }
        }
    }
    __syncthreads();

    // ---- softmax rows (cols 0..195); zero pad cols 196..255 ----
    {
        #pragma unroll
        for (int i = 0; i < 8; i++) {
            float* p = Ss + (wid * 8 + i) * 256;
            float v0 = p[lane], v1 = p[64 + lane], v2 = p[128 + lane];
            float v3 = (lane < 4) ? p[192 + lane] : -1e30f;
            float mx = fmaxf(fmaxf(v0, v1), fmaxf(v2, v3));
            #pragma unroll
            for (int off = 32; off > 0; off >>= 1) mx = fmaxf(mx, __shfl_xor(mx, off, 64));
            float e0 = expf(v0 - mx), e1 = expf(v1 - mx), e2 = expf(v2 - mx);
            float e3 = (lane < 4) ? expf(v3 - mx) : 0.f;
            float sum = e0 + e1 + e2 + e3;
            #pragma unroll
            for (int off = 32; off > 0; off >>= 1) sum += __shfl_xor(sum, off, 64);
            float inv = 1.f / sum;
            p[lane] = e0 * inv;
            p[64 + lane] = e1 * inv;
            p[128 + lane] = e2 * inv;
            if (lane < 4) p[192 + lane] = e3 * inv;
            else          p[192 + lane] = 0.f;            // pad cols 196..255
        }
    }
    __syncthreads();

    // ---- PV: out[32,32] = P[32,256] @ V[256(pad),32] ----
    {
        f32x4 acc0 = {0, 0, 0, 0}, acc1 = {0, 0, 0, 0};
        int nBl = (t >> 6) * 16 + (f & 15);               // 0..63, valid <32
        int kbB = (f >> 4) * 8;
        int mAl = ((t >> 6) & 1) * 16 + (f & 15);
        int kbA = (f >> 4) * 8;
        float ar[8], br[8];
        auto loadA = [&](int k0) {
            if (t < 128) {
                #pragma unroll
                for (int j = 0; j < 8; j++) ar[j] = Ss[mAl * 256 + k0 + kbA + j];
            }
        };
        auto loadB = [&](int k0) {
            #pragma unroll
            for (int j = 0; j < 8; j++) {
                int k = k0 + kbB + j;
                br[j] = (k < 196 && nBl < 32) ? Vb[(size_t)k * 768 + nBl] : 0.f;
            }
        };
        loadA(0); loadB(0);
        for (int k0 = 0; k0 < 256; k0 += 32) {
            __syncthreads();                              // As/Bs reuse guard
            if (t < 128) *(bshort8*)&As[(((t >> 6) & 1) * 512 + f * 8)] = pack8(ar);
            *(bshort8*)&Bs[((t >> 6) * 512 + f * 8)] = pack8(br);
            __syncthreads();
            if (k0 + 32 < 256) { loadA(k0 + 32); loadB(k0 + 32); }
            bshort8 av = *(const bshort8*)&As[wm * 512 + lane * 8];
            bshort8 bv0 = *(const bshort8*)&Bs[(wn * 2 + 0) * 512 + lane * 8];
            bshort8 bv1 = *(const bshort8*)&Bs[(wn * 2 + 1) * 512 + lane * 8];
            acc0 = mfma16(av, bv0, acc0);
            acc1 = mfma16(av, bv1, acc1);
        }
        int col0 = wn * 32 + (lane & 15);
        int rbase = wm * 16 + ((lane >> 4) << 2);
        if (col0 < 32) {
            #pragma unroll
            for (int r = 0; r < 4; r++) {
                int m = m0 + rbase + r;
                if (m < 196) {
                    xo[((size_t)b * 196 + m) * 256 + h * 32 + col0]      = acc0[r];
                    xo[((size_t)b * 196 + m) * 256 + h * 32 + col0 + 16] = acc1[r];
                }
            }
        }
    }
}

// ================= tail, stage 1: one block per (b,h) — 32 blocks =================
__global__ __launch_bounds__(1024) void tail1(
    const float* __restrict__ xo, const float* __restrict__ proj_w,
    const float* __restrict__ proj_b,
    const float* __restrict__ gat_W, const float* __restrict__ lemb,
    const float* __restrict__ Wa, const float* __restrict__ ldot,
    float* __restrict__ atts, float* __restrict__ hm_g)
{
    int b = blockIdx.x >> 2, h = blockIdx.x & 3;
    int t = threadIdx.x, lane = t & 63, wv = t >> 6;
    __shared__ float red[1024];
    __shared__ float xm[256];
    __shared__ float gctx_s[256];
    __shared__ float gdot_s[2];
    __shared__ float s12h[160];
    __shared__ float am_s[80];
    __shared__ float av_s[256];

    {
        int c = t & 255, sl = t >> 8;
        const float* base = xo + ((size_t)b * 196 + sl * 49) * 256 + c;
        float s = 0.f;
        #pragma unroll 7
        for (int i = 0; i < 49; i++) s += base[(size_t)i * 256];
        red[t] = s;
    }
    if (t < 80) am_s[t] = 0.f;
    __syncthreads();
    if (t < 256) xm[t] = (red[t] + red[256 + t] + red[512 + t] + red[768 + t]) * (1.f / 196.f);
    __syncthreads();

    {
        int n = t & 255, ks = t >> 8;
        float acc = 0.f;
        const float* w = proj_w + (size_t)(ks * 64) * 256 + n;
        #pragma unroll 8
        for (int i = 0; i < 64; i++) acc += xm[ks * 64 + i] * w[(size_t)i * 256];
        red[t] = acc;
    }
    __syncthreads();
    if (t < 256) gctx_s[t] = proj_b[t] + red[t] + red[256 + t] + red[512 + t] + red[768 + t];
    __syncthreads();

    if (wv < 2) {
        int pair = h * 2 + wv;
        const float* wa = Wa + pair * 256 + lane * 4;
        float p = gctx_s[lane * 4] * wa[0] + gctx_s[lane * 4 + 1] * wa[1]
                + gctx_s[lane * 4 + 2] * wa[2] + gctx_s[lane * 4 + 3] * wa[3];
        #pragma unroll
        for (int off = 32; off > 0; off >>= 1) p += __shfl_xor(p, off, 64);
        if (lane == 0) gdot_s[wv] = p;
    }
    __syncthreads();
    if (t < 160) {
        int q = t / 80, l = t - q * 80;
        s12h[t] = ldot[l * 8 + h * 2 + q] + gdot_s[q];
    }
    __syncthreads();

    {
        #pragma unroll
        for (int rr = 0; rr < 5; rr++) {
            int i = rr * 16 + wv;
            float s1i = s12h[i];
            const float* s2 = s12h + 80;
            float v0 = s1i + s2[lane]; v0 = v0 > 0.f ? v0 : 0.2f * v0;
            float v1 = -1e30f;
            if (lane < 16) { v1 = s1i + s2[64 + lane]; v1 = v1 > 0.f ? v1 : 0.2f * v1; }
            float mx = fmaxf(v0, v1);
            #pragma unroll
            for (int off = 32; off > 0; off >>= 1) mx = fmaxf(mx, __shfl_xor(mx, off, 64));
            float e0 = expf(v0 - mx), e1 = (lane < 16) ? expf(v1 - mx) : 0.f;
            float sum = e0 + e1;
            #pragma unroll
            for (int off = 32; off > 0; off >>= 1) sum += __shfl_xor(sum, off, 64);
            float inv = 1.f / sum;
            float* orow = atts + (size_t)h * 51200 + b * 6400 + i * 80;
            float p0 = e0 * inv;
            orow[lane] = p0;
            atomicAdd(&am_s[lane], p0);
            if (lane < 16) {
                float p1 = e1 * inv;
                orow[64 + lane] = p1;
                atomicAdd(&am_s[64 + lane], p1);
            }
        }
    }
    __syncthreads();

    {
        int n = t & 255, ks = t >> 8;
        float acc = 0.f;
        const float* le = lemb + n;
        #pragma unroll 5
        for (int l = ks * 20; l < ks * 20 + 20; l++) acc += am_s[l] * le[(size_t)l * 256];
        red[t] = acc;
    }
    __syncthreads();
    if (t < 256)
        av_s[t] = (red[t] + red[256 + t] + red[512 + t] + red[768 + t]) * (1.f / 80.f)
                + gctx_s[t];
    __syncthreads();
    {
        int n = t & 255, ks = t >> 8;
        float acc = 0.f;
        const float* w = gat_W + (size_t)h * 65536 + (size_t)(ks * 64) * 256 + n;
        #pragma unroll 8
        for (int i = 0; i < 64; i++) acc += av_s[ks * 64 + i] * w[(size_t)i * 256];
        red[t] = acc;
    }
    __syncthreads();
    if (t < 256)
        hm_g[(b * 4 + h) * 256 + t] = red[t] + red[256 + t] + red[512 + t] + red[768 + t];
}

// ================= tail, stage 2: one block per b — 8 blocks =================
__global__ __launch_bounds__(1024) void tail2(
    const float* __restrict__ hm_g,
    const float* __restrict__ out_w, const float* __restrict__ out_b,
    const float* __restrict__ spec_w1, const float* __restrict__ spec_b1,
    const float* __restrict__ spec_w2, const float* __restrict__ spec_b2,
    const float* __restrict__ spat_w1, const float* __restrict__ spat_b1,
    const float* __restrict__ spat_w2, const float* __restrict__ spat_b2,
    const float* __restrict__ gate_w, const float* __restrict__ gate_b,
    const float* __restrict__ unc_w, const float* __restrict__ unc_b,
    float* __restrict__ out)
{
    int b = blockIdx.x, t = threadIdx.x;
    __shared__ float red[1024];
    __shared__ float as_s[256];
    __shared__ float hb_s[256];
    __shared__ float fv_s[320];

    {
        int n = t & 255, ks = t >> 8;
        float acc = 0.f;
        const float* hv = hm_g + b * 1024 + ks * 256;
        const float* w = out_w + (size_t)(ks * 256) * 256 + n;
        #pragma unroll 8
        for (int k = 0; k < 256; k++) acc += hv[k] * w[(size_t)k * 256];
        red[t] = acc;
    }
    __syncthreads();
    if (t < 256) as_s[t] = out_b[t] + red[t] + red[256 + t] + red[512 + t] + red[768 + t];
    __syncthreads();

    {
        int u = t & 255, ks = t >> 8;
        int which = u >> 7, oo = u & 127;
        const float* w1 = which ? spat_w1 : spec_w1;
        float acc = 0.f;
        #pragma unroll 8
        for (int i = 0; i < 64; i++) {
            int k = ks * 64 + i;
            acc += as_s[k] * w1[(size_t)k * 128 + oo];
        }
        red[t] = acc;
    }
    __syncthreads();
    if (t < 256) {
        int which = t >> 7, oo = t & 127;
        const float* b1 = which ? spat_b1 : spec_b1;
        hb_s[t] = fmaxf(red[t] + red[256 + t] + red[512 + t] + red[768 + t] + b1[oo], 0.f);
    }
    __syncthreads();

    if (t < 960) {
        int sub = t / 320, u = t - sub * 320;
        int head = u / 80, o = u - head * 80;
        const float* wp; const float* src; int K;
        if (head == 0)      { wp = spec_w2; src = hb_s;       K = 128; }
        else if (head == 1) { wp = spat_w2; src = hb_s + 128; K = 128; }
        else if (head == 2) { wp = gate_w;  src = as_s;       K = 256; }
        else                { wp = unc_w;   src = as_s;       K = 256; }
        int k0 = (K * sub) / 3, k1 = (K * (sub + 1)) / 3;
        float acc = 0.f;
        for (int k = k0; k < k1; k++) acc += src[k] * wp[(size_t)k * 80 + o];
        red[sub * 320 + u] = acc;
    }
    __syncthreads();
    if (t < 320) {
        int head = t / 80, o = t - head * 80;
        const float* bp = head == 0 ? spec_b2 : head == 1 ? spat_b2 : head == 2 ? gate_b : unc_b;
        fv_s[t] = red[t] + red[320 + t] + red[640 + t] + bp[o];
    }
    __syncthreads();

    if (t < 80) {
        float sp = fv_s[t], st2 = fv_s[80 + t], gz = fv_s[160 + t], uz = fv_s[240 + t];
        float g = 1.f / (1.f + expf(-gz));
        out[b * 80 + t] = g * sp + (1.f - g) * st2;
        out[640 + b * 80 + t] = sp;
        out[1280 + b * 80 + t] = st2;
        out[1920 + b * 80 + t] = g;
        red[t] = log1pf(expf(uz)) + 1.f;
    }
    __syncthreads();
    if (t == 0) {
        float s = 0.f;
        for (int l = 0; l < 80; l++) s += red[l];
        out[2560 + b] = 80.f / s;
    }
}

// ---------------- launcher ----------------
extern "C" void kernel_launch(void* const* d_in, const int* in_sizes, int n_in,
                              void* d_out, int out_size, void* d_ws, size_t ws_size,
                              hipStream_t stream)
{
    (void)in_sizes; (void)n_in; (void)out_size; (void)ws_size;
    const float* c2 = (const float*)d_in[0];
    const float* c3 = (const float*)d_in[1];
    const float* c4 = (const float*)d_in[2];
    const float* c5 = (const float*)d_in[3];
    const float* lat_w0 = (const float*)d_in[4];
    const float* lat_b0 = (const float*)d_in[5];
    const float* lat_w1 = (const float*)d_in[6];
    const float* lat_b1 = (const float*)d_in[7];
    const float* lat_w2 = (const float*)d_in[8];
    const float* lat_b2 = (const float*)d_in[9];
    const float* lat_w3 = (const float*)d_in[10];
    const float* lat_b3 = (const float*)d_in[11];
    const float* sp_w1 = (const float*)d_in[12];
    const float* sp_b1 = (const float*)d_in[13];
    const float* sp_w2 = (const float*)d_in[14];
    const float* sp_b2 = (const float*)d_in[15];
    const float* qkv_w = (const float*)d_in[16];
    const float* qkv_b = (const float*)d_in[17];
    const float* proj_w = (const float*)d_in[18];
    const float* proj_b = (const float*)d_in[19];
    const float* gat_W = (const float*)d_in[20];
    const float* gat_a = (const float*)d_in[21];
    const float* out_w = (const float*)d_in[22];
    const float* out_b = (const float*)d_in[23];
    const float* label_emb = (const float*)d_in[24];
    const float* spec_w1 = (const float*)d_in[25];
    const float* spec_b1 = (const float*)d_in[26];
    const float* spec_w2 = (const float*)d_in[27];
    const float* spec_b2 = (const float*)d_in[28];
    const float* spat_w1 = (const float*)d_in[29];
    const float* spat_b1 = (const float*)d_in[30];
    const float* spat_w2 = (const float*)d_in[31];
    const float* spat_b2 = (const float*)d_in[32];
    const float* gate_w = (const float*)d_in[33];
    const float* gate_b = (const float*)d_in[34];
    const float* unc_w = (const float*)d_in[35];
    const float* unc_b = (const float*)d_in[36];

    float* out = (float*)d_out;
    float* ws = (float*)d_ws;

    // workspace layout (floats); pf buffers bf16 (ushort) in same regions
    unsigned short* pf0 = (unsigned short*)(ws + 0);        // 401408 elems
    unsigned short* pf1 = (unsigned short*)(ws + 401408);   // 802816
    unsigned short* pf2 = (unsigned short*)(ws + 1204224);  // 1605632
    unsigned short* pf3 = (unsigned short*)(ws + 2809856);  // 3211264 (ends 6021120)
    float* pooled = ws + 6021120;  // 16384  -> 6037504
    float* swpart = ws + 6039552;  // 32768  -> 6072320
    float* Wa     = ws + 6072320;  // 2048   -> 6074368
    float* ldot   = ws + 6074368;  // 640    -> 6075008
    float* qkv    = ws + 0;        // reuses pf0/pf1 region (dead after lateral)
    float* xo     = ws + 3662848;  // 401408 -> 4064256
    float* hm_g   = ws + 4253696;  // 8192   -> 4261888
    float* xtok   = ws + 6106112;  // 401408 -> 6507520

    float* swp  = out + 2568;  // sw [8,4] (output 5)
    float* atts = out + 2600;  // atts [4,8,80,80] (output 6)

    // 1. ALL pools (bf16 out, LDS-staged planes) + fused c5 mean
    pool_all<<<17952, 256, 0, stream>>>(c2, c3, c4, c5, pf0, pf1, pf2, pf3, pooled);
    // 2. scale-weight MLP partials + hoisted Wa (16 extra blocks)
    sw_part<<<dim3(8, 10), 512, 0, stream>>>(pooled, sp_w1, swpart, gat_W, gat_a, Wa);
    // 2b. finish sw MLP + bias-init xtok + hoisted ldot
    sw_fin<<<8, 512, 0, stream>>>(swpart, sp_b1, sp_w2, sp_b2,
                                  lat_b0, lat_b1, lat_b2, lat_b3,
                                  label_emb, Wa, swp, xtok, ldot);
    // 3. lateral projection (bf16 pf direct-load, sw in epilogue) -> xtok [1568,256]
    lateral_slice<<<dim3(196, 8), 256, 0, stream>>>(pf0, pf1, pf2, pf3,
                                                    lat_w0, lat_w1, lat_w2, lat_w3,
                                                    swp, xtok);
    // 4. qkv = x @ qkv_w + qkv_b : [1568,768]
    gemm_kernel<true><<<dim3(49 * 12, 1, 1), 256, 0, stream>>>(
        xtok, 256, 0, 0, qkv_w, 768, 0, 0, qkv, 768, 0, 0,
        qkv_b, 1568, 768, 256, 1.f, 49);
    // 5. fused attention: S, softmax, PV in one kernel -> xo [1568,256]
    fused_attn<<<dim3(7, 8, 8), 256, 0, stream>>>(qkv, xo);
    // 6. tail stage 1: per (b,h) — gctx/s12/softmax/av/hm (32 blocks)
    tail1<<<32, 1024, 0, stream>>>(xo, proj_w, proj_b, gat_W, label_emb,
                                   Wa, ldot, atts, hm_g);
    // 7. tail stage 2: per b — a_s/MLPs/heads/combine (8 blocks)
    tail2<<<8, 1024, 0, stream>>>(hm_g, out_w, out_b,
                                  spec_w1, spec_b1, spec_w2, spec_b2,
                                  spat_w1, spat_b1, spat_w2, spat_b2,
                                  gate_w, gate_b, unc_w, unc_b, out);
}